// Round 11
// baseline (96.738 us; speedup 1.0000x reference)
//
#include <hip/hip_runtime.h>
#include <hip/hip_bf16.h>

#define HH 128
#define WW 128
#define HWSZ (HH * WW)   // 16384
#define CC 64
#define BB 2
#define KK 7
#define K2 49
#define ROWE 280         // bf16 elems/padded row: [Eph0 70][Eph1 70][Oph0 70][Oph1 70]

typedef unsigned int u32;

__device__ __forceinline__ int clampi(int v, int lo, int hi) {
    return v < lo ? lo : (v > hi ? hi : v);
}

__device__ __forceinline__ uint4 ld16(const __hip_bfloat16* src) {
    uint4 d; __builtin_memcpy(&d, src, 16); return d;   // 4B-aligned dwordx4
}

// 8 packed bf16 (4 dwords) -> 8 fp32. elem 2k = lo half of dword k.
__device__ __forceinline__ void unpack8(uint4 d, float* f) {
    f[0] = __uint_as_float(d.x << 16); f[1] = __uint_as_float(d.x & 0xffff0000u);
    f[2] = __uint_as_float(d.y << 16); f[3] = __uint_as_float(d.y & 0xffff0000u);
    f[4] = __uint_as_float(d.z << 16); f[5] = __uint_as_float(d.z & 0xffff0000u);
    f[6] = __uint_as_float(d.w << 16); f[7] = __uint_as_float(d.w & 0xffff0000u);
}

__device__ __forceinline__ unsigned short f2bf(float v) {
    __hip_bfloat16 b = __float2bfloat16(v);
    return *reinterpret_cast<unsigned short*>(&b);
}

// Store one K/V value into the phase-duplicated parity row + edge pads.
__device__ __forceinline__ void store_kv(__hip_bfloat16* rowp, int w, float val) {
    const int parity = w & 1, t = w >> 1;
    const int pb = parity * 140;
    __hip_bfloat16 bv = __float2bfloat16(val);
    rowp[pb + 3 + t]  = bv;        // phase0: P[t+3]
    rowp[pb + 72 + t] = bv;        // phase1: P1[t+2]
    if (w == 0) {
#pragma unroll
        for (int u = 0; u < 3; ++u) { rowp[u] = bv; rowp[140 + u] = bv; }
#pragma unroll
        for (int u = 0; u < 2; ++u) { rowp[70 + u] = bv; rowp[210 + u] = bv; }
    }
    if (w == 127) {
#pragma unroll
        for (int u = 0; u < 3; ++u) { rowp[67 + u] = bv; rowp[140 + 67 + u] = bv; }
#pragma unroll
        for (int u = 0; u < 4; ++u) { rowp[70 + 66 + u] = bv; rowp[210 + 66 + u] = bv; }
    }
}

// per-lane window offset: 7-neighbor window = first 7 elems of one aligned 16B load
__device__ __forceinline__ int lane_off(int w) {
    const int parity = w & 1, t = w >> 1, phase = t & 1;
    return parity * 140 + phase * 70 + (t - phase);
}

// ---------------------------------------------------------------------------
// K1: K/Q/V = relu(W @ x). Grid 1024 = xcd(8) x [pb16 x og8].
// ---------------------------------------------------------------------------
__global__ __launch_bounds__(256) void kqv_kernel(
    const float* __restrict__ x,  const float* __restrict__ Wk,
    const float* __restrict__ Wq, const float* __restrict__ Wv,
    __hip_bfloat16* __restrict__ Kp, __hip_bfloat16* __restrict__ Qt,
    __hip_bfloat16* __restrict__ Vp)
{
    const int xcd = blockIdx.x & 7;
    const int s   = blockIdx.x >> 3;          // 0..127
    const int pb  = xcd * 16 + (s & 15);      // 0..127
    const int og  = s >> 4;                   // 0..7
    const int p   = pb * 256 + threadIdx.x;   // 0..32767
    const int b   = p >> 14;
    const int hw  = p & 16383;
    const int h   = hw >> 7;
    const int w   = hw & 127;
    const int o0  = og * 8;
    const float* xp = x + (size_t)b * CC * HWSZ + hw;

    float aK[8], aQ[8], aV[8];
#pragma unroll
    for (int i = 0; i < 8; ++i) { aK[i] = 0.f; aQ[i] = 0.f; aV[i] = 0.f; }

#pragma unroll 8
    for (int c = 0; c < CC; ++c) {
        const float xv = xp[(size_t)c * HWSZ];
#pragma unroll
        for (int i = 0; i < 8; ++i) {
            aK[i] = fmaf(Wk[(o0 + i) * CC + c], xv, aK[i]);
            aQ[i] = fmaf(Wq[(o0 + i) * CC + c], xv, aQ[i]);
            aV[i] = fmaf(Wv[(o0 + i) * CC + c], xv, aV[i]);
        }
    }

#pragma unroll
    for (int i = 0; i < 8; ++i) {
        __hip_bfloat16* krow = Kp + ((size_t)(b * CC + o0 + i) * HH + h) * ROWE;
        __hip_bfloat16* vrow = Vp + ((size_t)(b * CC + o0 + i) * HH + h) * ROWE;
        store_kv(krow, w, fmaxf(aK[i], 0.f));
        store_kv(vrow, w, fmaxf(aV[i], 0.f));
    }

    u32 qd[4];
#pragma unroll
    for (int i = 0; i < 4; ++i)
        qd[i] = (u32)f2bf(fmaxf(aQ[2 * i], 0.f)) |
                ((u32)f2bf(fmaxf(aQ[2 * i + 1], 0.f)) << 16);
    __builtin_memcpy(Qt + (size_t)p * CC + o0, qd, 16);   // 16B aligned
}

// ---------------------------------------------------------------------------
// K2: FUSED scores + softmax + V-aggregate, software-pipelined.
// Grid 1024 = xcd(8) x [bh32 x wseg4], 256 thr: px 0..31, cq 0..7.
// Phase A/B: 2-deep channel double-buffer (loads of ci+1 in flight during
// compute of ci). V ci=0 prefetched before the reduce/softmax section.
// ---------------------------------------------------------------------------
__global__ __launch_bounds__(256) void attn_kernel(
    const __hip_bfloat16* __restrict__ Kp, const __hip_bfloat16* __restrict__ Qt,
    const __hip_bfloat16* __restrict__ Vp, __hip_bfloat16* __restrict__ Ot)
{
    __shared__ float part[2][K2][33];

    const int xcd  = blockIdx.x & 7;
    const int s    = blockIdx.x >> 3;       // 0..127
    const int bh   = xcd * 32 + (s >> 2);   // 0..255
    const int wseg = s & 3;
    const int b    = bh >> 7;
    const int h    = bh & 127;

    const int tid = threadIdx.x;
    const int px  = (tid & 15) | ((tid >> 7) << 4);   // 0..31
    const int cq  = (tid >> 4) & 7;                   // 0..7
    const int w   = wseg * 32 + px;                   // 0..127
    const int p   = b * HWSZ + h * WW + w;
    const int c0  = cq * 8;

    size_t ro[KK];
#pragma unroll
    for (int i = 0; i < KK; ++i)
        ro[i] = (size_t)clampi(h + 2 * i - 6, 0, HH - 1) * ROWE;

    const int loff = lane_off(w);
    const size_t cstride = (size_t)HH * ROWE;
    const __hip_bfloat16* Kc = Kp + (size_t)(b * CC + c0) * cstride + loff;
    const __hip_bfloat16* Vc = Vp + (size_t)(b * CC + c0) * cstride + loff;

    float qf[8];
    unpack8(ld16(Qt + (size_t)p * CC + c0), qf);

    // ---- Phase A: partial scores, pipelined over 8 channels ----
    float sc[K2];
#pragma unroll
    for (int k = 0; k < K2; ++k) sc[k] = 0.f;

    uint4 bufA[KK], bufB[KK];
#pragma unroll
    for (int i = 0; i < KK; ++i) bufA[i] = ld16(Kc + ro[i]);

#pragma unroll
    for (int ci = 0; ci < 8; ++ci) {
        const uint4* cur = (ci & 1) ? bufB : bufA;
        uint4*       nxt = (ci & 1) ? bufA : bufB;
        if (ci < 7) {
            const __hip_bfloat16* nb = Kc + (size_t)(ci + 1) * cstride;
#pragma unroll
            for (int i = 0; i < KK; ++i) nxt[i] = ld16(nb + ro[i]);
        }
        const float qv = qf[ci];
#pragma unroll
        for (int i = 0; i < KK; ++i) {
            float kf[8];
            unpack8(cur[i], kf);
#pragma unroll
            for (int j = 0; j < KK; ++j)
                sc[i * KK + j] = fmaf(kf[j], qv, sc[i * KK + j]);
        }
    }

    // prefetch V ci=0 before the serial reduce/softmax section
    uint4 vpre[KK];
#pragma unroll
    for (int i = 0; i < KK; ++i) vpre[i] = ld16(Vc + ro[i]);

    // ---- cq-reduction: shfl (4 per wave) + LDS (2 slices) ----
#pragma unroll
    for (int k = 0; k < K2; ++k) sc[k] += __shfl_xor(sc[k], 16, 64);
#pragma unroll
    for (int k = 0; k < K2; ++k) sc[k] += __shfl_xor(sc[k], 32, 64);

    const int sl = (tid >> 6) & 1;
    if (((tid >> 4) & 3) == 0) {
#pragma unroll
        for (int k = 0; k < K2; ++k) part[sl][k][px] = sc[k];
    }
    __syncthreads();

    // ---- softmax (per thread, redundant x8, deterministic) ----
#pragma unroll
    for (int k = 0; k < K2; ++k) sc[k] = part[0][k][px] + part[1][k][px];
    float m = sc[0];
#pragma unroll
    for (int k = 1; k < K2; ++k) m = fmaxf(m, sc[k]);
    float sum = 0.f;
#pragma unroll
    for (int k = 0; k < K2; ++k) { sc[k] = __expf(sc[k] - m); sum += sc[k]; }
    const float inv = 1.f / sum;
#pragma unroll
    for (int k = 0; k < K2; ++k) sc[k] *= inv;

    // ---- Phase B: V-aggregate, pipelined over 8 channels ----
    unsigned short ob[8];
#pragma unroll
    for (int i = 0; i < KK; ++i) bufA[i] = vpre[i];

#pragma unroll
    for (int ci = 0; ci < 8; ++ci) {
        const uint4* cur = (ci & 1) ? bufB : bufA;
        uint4*       nxt = (ci & 1) ? bufA : bufB;
        if (ci < 7) {
            const __hip_bfloat16* nb = Vc + (size_t)(ci + 1) * cstride;
#pragma unroll
            for (int i = 0; i < KK; ++i) nxt[i] = ld16(nb + ro[i]);
        }
        float acc = 0.f;
#pragma unroll
        for (int i = 0; i < KK; ++i) {
            float vf[8];
            unpack8(cur[i], vf);
#pragma unroll
            for (int j = 0; j < KK; ++j)
                acc = fmaf(vf[j], sc[i * KK + j], acc);
        }
        ob[ci] = f2bf(acc);
    }

    u32 od[4];
#pragma unroll
    for (int i = 0; i < 4; ++i)
        od[i] = (u32)ob[2 * i] | ((u32)ob[2 * i + 1] << 16);
    __builtin_memcpy(Ot + (size_t)p * CC + c0, od, 16);   // 16B aligned
}

// ---------------------------------------------------------------------------
// K3: out = Wt @ O + x. Grid 1024 = xcd(8) x [pb16 x og8].
// ---------------------------------------------------------------------------
__global__ __launch_bounds__(256) void wt_kernel(
    const __hip_bfloat16* __restrict__ Ot, const float* __restrict__ x,
    const float* __restrict__ Wt, float* __restrict__ out)
{
    const int xcd = blockIdx.x & 7;
    const int s   = blockIdx.x >> 3;        // 0..127
    const int pb  = xcd * 16 + (s & 15);
    const int og  = s >> 4;
    const int p   = pb * 256 + threadIdx.x;
    const int b   = p >> 14;
    const int hw  = p & 16383;
    const int o0  = og * 8;

    float fin[8];
#pragma unroll
    for (int i = 0; i < 8; ++i)
        fin[i] = x[((size_t)b * CC + o0 + i) * HWSZ + hw];

    const __hip_bfloat16* op = Ot + (size_t)p * CC;
#pragma unroll
    for (int k = 0; k < 8; ++k) {
        float oc[8];
        unpack8(ld16(op + 8 * k), oc);
#pragma unroll
        for (int cc = 0; cc < 8; ++cc) {
            const int c = 8 * k + cc;
#pragma unroll
            for (int i = 0; i < 8; ++i)
                fin[i] = fmaf(Wt[(o0 + i) * CC + c], oc[cc], fin[i]);
        }
    }

#pragma unroll
    for (int i = 0; i < 8; ++i)
        out[((size_t)b * CC + o0 + i) * HWSZ + hw] = fin[i];
}

// ---------------------------------------------------------------------------
extern "C" void kernel_launch(void* const* d_in, const int* in_sizes, int n_in,
                              void* d_out, int out_size, void* d_ws, size_t ws_size,
                              hipStream_t stream)
{
    const float* x  = (const float*)d_in[0];
    const float* Wk = (const float*)d_in[1];
    const float* Wq = (const float*)d_in[2];
    const float* Wv = (const float*)d_in[3];
    const float* Wt = (const float*)d_in[4];
    float* out = (float*)d_out;

    const size_t KP_ELEMS = (size_t)BB * CC * HH * ROWE;  // 4,587,520 bf16
    const size_t QT_ELEMS = (size_t)BB * HWSZ * CC;       // 2,097,152 bf16
    __hip_bfloat16* Kp = (__hip_bfloat16*)d_ws;
    __hip_bfloat16* Vp = Kp + KP_ELEMS;
    __hip_bfloat16* Qt = Vp + KP_ELEMS;
    __hip_bfloat16* Ot = Qt + QT_ELEMS;                   // total ws 26.8 MB

    hipLaunchKernelGGL(kqv_kernel, dim3(1024), dim3(256), 0, stream,
                       x, Wk, Wq, Wv, Kp, Qt, Vp);
    hipLaunchKernelGGL(attn_kernel, dim3(1024), dim3(256), 0, stream,
                       Kp, Qt, Vp, Ot);
    hipLaunchKernelGGL(wt_kernel, dim3(1024), dim3(256), 0, stream,
                       Ot, x, Wt, out);
}

// Round 13
// 91.815 us; speedup vs baseline: 1.0536x; 1.0536x over previous
//
#include <hip/hip_runtime.h>
#include <hip/hip_bf16.h>

#define HH 128
#define WW 128
#define HWSZ (HH * WW)   // 16384
#define CC 64
#define BB 2
#define KK 7
#define K2 49
#define ROWE 280         // bf16 elems/padded row: [Eph0 70][Eph1 70][Oph0 70][Oph1 70]

typedef unsigned int u32;

__device__ __forceinline__ int clampi(int v, int lo, int hi) {
    return v < lo ? lo : (v > hi ? hi : v);
}

__device__ __forceinline__ uint4 ld16(const __hip_bfloat16* src) {
    uint4 d; __builtin_memcpy(&d, src, 16); return d;   // 4B-aligned dwordx4
}

// 8 packed bf16 (4 dwords) -> 8 fp32. elem 2k = lo half of dword k.
__device__ __forceinline__ void unpack8(uint4 d, float* f) {
    f[0] = __uint_as_float(d.x << 16); f[1] = __uint_as_float(d.x & 0xffff0000u);
    f[2] = __uint_as_float(d.y << 16); f[3] = __uint_as_float(d.y & 0xffff0000u);
    f[4] = __uint_as_float(d.z << 16); f[5] = __uint_as_float(d.z & 0xffff0000u);
    f[6] = __uint_as_float(d.w << 16); f[7] = __uint_as_float(d.w & 0xffff0000u);
}

__device__ __forceinline__ unsigned short f2bf(float v) {
    __hip_bfloat16 b = __float2bfloat16(v);
    return *reinterpret_cast<unsigned short*>(&b);
}

// Store one K/V value into the phase-duplicated parity row + edge pads.
__device__ __forceinline__ void store_kv(__hip_bfloat16* rowp, int w, float val) {
    const int parity = w & 1, t = w >> 1;
    const int pb = parity * 140;
    __hip_bfloat16 bv = __float2bfloat16(val);
    rowp[pb + 3 + t]  = bv;        // phase0: P[t+3]
    rowp[pb + 72 + t] = bv;        // phase1: P1[t+2]
    if (w == 0) {
#pragma unroll
        for (int u = 0; u < 3; ++u) { rowp[u] = bv; rowp[140 + u] = bv; }
#pragma unroll
        for (int u = 0; u < 2; ++u) { rowp[70 + u] = bv; rowp[210 + u] = bv; }
    }
    if (w == 127) {
#pragma unroll
        for (int u = 0; u < 3; ++u) { rowp[67 + u] = bv; rowp[140 + 67 + u] = bv; }
#pragma unroll
        for (int u = 0; u < 4; ++u) { rowp[70 + 66 + u] = bv; rowp[210 + 66 + u] = bv; }
    }
}

// per-lane window offset: 7-neighbor window = first 7 elems of one aligned 16B load
__device__ __forceinline__ int lane_off(int w) {
    const int parity = w & 1, t = w >> 1, phase = t & 1;
    return parity * 140 + phase * 70 + (t - phase);
}

// ---------------------------------------------------------------------------
// K1: K/Q/V = relu(W @ x). Grid 1024 = xcd(8) x [pb16 x og8].
// ---------------------------------------------------------------------------
__global__ __launch_bounds__(256) void kqv_kernel(
    const float* __restrict__ x,  const float* __restrict__ Wk,
    const float* __restrict__ Wq, const float* __restrict__ Wv,
    __hip_bfloat16* __restrict__ Kp, __hip_bfloat16* __restrict__ Qt,
    __hip_bfloat16* __restrict__ Vp)
{
    const int xcd = blockIdx.x & 7;
    const int s   = blockIdx.x >> 3;          // 0..127
    const int pb  = xcd * 16 + (s & 15);      // 0..127
    const int og  = s >> 4;                   // 0..7
    const int p   = pb * 256 + threadIdx.x;   // 0..32767
    const int b   = p >> 14;
    const int hw  = p & 16383;
    const int h   = hw >> 7;
    const int w   = hw & 127;
    const int o0  = og * 8;
    const float* xp = x + (size_t)b * CC * HWSZ + hw;

    float aK[8], aQ[8], aV[8];
#pragma unroll
    for (int i = 0; i < 8; ++i) { aK[i] = 0.f; aQ[i] = 0.f; aV[i] = 0.f; }

#pragma unroll 8
    for (int c = 0; c < CC; ++c) {
        const float xv = xp[(size_t)c * HWSZ];
#pragma unroll
        for (int i = 0; i < 8; ++i) {
            aK[i] = fmaf(Wk[(o0 + i) * CC + c], xv, aK[i]);
            aQ[i] = fmaf(Wq[(o0 + i) * CC + c], xv, aQ[i]);
            aV[i] = fmaf(Wv[(o0 + i) * CC + c], xv, aV[i]);
        }
    }

#pragma unroll
    for (int i = 0; i < 8; ++i) {
        __hip_bfloat16* krow = Kp + ((size_t)(b * CC + o0 + i) * HH + h) * ROWE;
        __hip_bfloat16* vrow = Vp + ((size_t)(b * CC + o0 + i) * HH + h) * ROWE;
        store_kv(krow, w, fmaxf(aK[i], 0.f));
        store_kv(vrow, w, fmaxf(aV[i], 0.f));
    }

    u32 qd[4];
#pragma unroll
    for (int i = 0; i < 4; ++i)
        qd[i] = (u32)f2bf(fmaxf(aQ[2 * i], 0.f)) |
                ((u32)f2bf(fmaxf(aQ[2 * i + 1], 0.f)) << 16);
    __builtin_memcpy(Qt + (size_t)p * CC + o0, qd, 16);   // 16B aligned
}

// ---------------------------------------------------------------------------
// K2: FUSED scores + softmax + V-aggregate, low-VGPR layout.
// Grid 1024 = xcd(8) x [bh32 x wseg4], 256 thr: px = tid&31 (pixel),
// grp = tid>>5 (0..7).
// Phase A: grp<7 computes score ROW i=grp (sc[7]) over all 64 channels
//          -> writes to LDS tile P_lds[px][49]. No cross-thread reduction.
// Softmax: per-thread from LDS (13 aligned float4), redundant x8.
// Phase B: grp = 8-channel group; aggregates via 7 window loads/channel.
// ---------------------------------------------------------------------------
__global__ __launch_bounds__(256) void attn_kernel(
    const __hip_bfloat16* __restrict__ Kp, const __hip_bfloat16* __restrict__ Qt,
    const __hip_bfloat16* __restrict__ Vp, __hip_bfloat16* __restrict__ Ot)
{
    __shared__ __align__(16) float P_lds[32][52];

    const int xcd  = blockIdx.x & 7;
    const int s    = blockIdx.x >> 3;       // 0..127
    const int bh   = xcd * 32 + (s >> 2);   // 0..255
    const int wseg = s & 3;
    const int b    = bh >> 7;
    const int h    = bh & 127;

    const int tid = threadIdx.x;
    const int px  = tid & 31;
    const int grp = tid >> 5;               // 0..7
    const int w   = wseg * 32 + px;
    const int p   = b * HWSZ + h * WW + w;

    const int loff = lane_off(w);
    const size_t cstride = (size_t)HH * ROWE;

    // ---- Phase A: score row i = grp (7 of 8 groups active) ----
    if (grp < 7) {
        const int rowoff = clampi(h + 2 * grp - 6, 0, HH - 1) * ROWE;
        const __hip_bfloat16* Kc = Kp + (size_t)(b * CC) * cstride + rowoff + loff;
        const __hip_bfloat16* Qp = Qt + (size_t)p * CC;

        float sc7[KK];
#pragma unroll
        for (int j = 0; j < KK; ++j) sc7[j] = 0.f;

#pragma unroll 2
        for (int c8 = 0; c8 < 8; ++c8) {
            float qf[8];
            unpack8(ld16(Qp + c8 * 8), qf);
#pragma unroll
            for (int cc = 0; cc < 8; ++cc) {
                float kf[8];
                unpack8(ld16(Kc + (size_t)(c8 * 8 + cc) * cstride), kf);
#pragma unroll
                for (int j = 0; j < KK; ++j)
                    sc7[j] = fmaf(kf[j], qf[cc], sc7[j]);
            }
        }
#pragma unroll
        for (int j = 0; j < KK; ++j) P_lds[px][grp * KK + j] = sc7[j];
    }
    __syncthreads();

    // ---- softmax (per thread, redundant x8, deterministic) ----
    float pr[52];
#pragma unroll
    for (int t = 0; t < 13; ++t)
        ((float4*)pr)[t] = ((const float4*)&P_lds[px][0])[t];
    float m = pr[0];
#pragma unroll
    for (int k = 1; k < K2; ++k) m = fmaxf(m, pr[k]);
    float sum = 0.f;
#pragma unroll
    for (int k = 0; k < K2; ++k) { pr[k] = __expf(pr[k] - m); sum += pr[k]; }
    const float inv = 1.f / sum;
#pragma unroll
    for (int k = 0; k < K2; ++k) pr[k] *= inv;

    // ---- Phase B: V-aggregate for this group's 8 output channels ----
    int ro[KK];
#pragma unroll
    for (int i = 0; i < KK; ++i)
        ro[i] = clampi(h + 2 * i - 6, 0, HH - 1) * ROWE;

    const int c0 = grp * 8;
    const __hip_bfloat16* Vc = Vp + (size_t)(b * CC + c0) * cstride + loff;

    unsigned short ob[8];
#pragma unroll 2
    for (int ci = 0; ci < 8; ++ci) {
        const __hip_bfloat16* base = Vc + (size_t)ci * cstride;
        float acc = 0.f;
#pragma unroll
        for (int i = 0; i < KK; ++i) {
            float vf[8];
            unpack8(ld16(base + ro[i]), vf);
#pragma unroll
            for (int j = 0; j < KK; ++j)
                acc = fmaf(vf[j], pr[i * KK + j], acc);
        }
        ob[ci] = f2bf(acc);
    }

    u32 od[4];
#pragma unroll
    for (int i = 0; i < 4; ++i)
        od[i] = (u32)ob[2 * i] | ((u32)ob[2 * i + 1] << 16);
    __builtin_memcpy(Ot + (size_t)p * CC + c0, od, 16);   // 16B aligned
}

// ---------------------------------------------------------------------------
// K3: out = Wt @ O + x. Grid 1024 = xcd(8) x [pb16 x og8].
// ---------------------------------------------------------------------------
__global__ __launch_bounds__(256) void wt_kernel(
    const __hip_bfloat16* __restrict__ Ot, const float* __restrict__ x,
    const float* __restrict__ Wt, float* __restrict__ out)
{
    const int xcd = blockIdx.x & 7;
    const int s   = blockIdx.x >> 3;        // 0..127
    const int pb  = xcd * 16 + (s & 15);
    const int og  = s >> 4;
    const int p   = pb * 256 + threadIdx.x;
    const int b   = p >> 14;
    const int hw  = p & 16383;
    const int o0  = og * 8;

    float fin[8];
#pragma unroll
    for (int i = 0; i < 8; ++i)
        fin[i] = x[((size_t)b * CC + o0 + i) * HWSZ + hw];

    const __hip_bfloat16* op = Ot + (size_t)p * CC;
#pragma unroll
    for (int k = 0; k < 8; ++k) {
        float oc[8];
        unpack8(ld16(op + 8 * k), oc);
#pragma unroll
        for (int cc = 0; cc < 8; ++cc) {
            const int c = 8 * k + cc;
#pragma unroll
            for (int i = 0; i < 8; ++i)
                fin[i] = fmaf(Wt[(o0 + i) * CC + c], oc[cc], fin[i]);
        }
    }

#pragma unroll
    for (int i = 0; i < 8; ++i)
        out[((size_t)b * CC + o0 + i) * HWSZ + hw] = fin[i];
}

// ---------------------------------------------------------------------------
extern "C" void kernel_launch(void* const* d_in, const int* in_sizes, int n_in,
                              void* d_out, int out_size, void* d_ws, size_t ws_size,
                              hipStream_t stream)
{
    const float* x  = (const float*)d_in[0];
    const float* Wk = (const float*)d_in[1];
    const float* Wq = (const float*)d_in[2];
    const float* Wv = (const float*)d_in[3];
    const float* Wt = (const float*)d_in[4];
    float* out = (float*)d_out;

    const size_t KP_ELEMS = (size_t)BB * CC * HH * ROWE;  // 4,587,520 bf16
    const size_t QT_ELEMS = (size_t)BB * HWSZ * CC;       // 2,097,152 bf16
    __hip_bfloat16* Kp = (__hip_bfloat16*)d_ws;
    __hip_bfloat16* Vp = Kp + KP_ELEMS;
    __hip_bfloat16* Qt = Vp + KP_ELEMS;
    __hip_bfloat16* Ot = Qt + QT_ELEMS;                   // total ws 26.8 MB

    hipLaunchKernelGGL(kqv_kernel, dim3(1024), dim3(256), 0, stream,
                       x, Wk, Wq, Wv, Kp, Qt, Vp);
    hipLaunchKernelGGL(attn_kernel, dim3(1024), dim3(256), 0, stream,
                       Kp, Qt, Vp, Ot);
    hipLaunchKernelGGL(wt_kernel, dim3(1024), dim3(256), 0, stream,
                       Ot, x, Wt, out);
}

// Round 16
// 90.501 us; speedup vs baseline: 1.0689x; 1.0145x over previous
//
#include <hip/hip_runtime.h>
#include <hip/hip_bf16.h>

#define HH 128
#define WW 128
#define HWSZ (HH * WW)   // 16384
#define CC 64
#define BB 2
#define KK 7
#define K2 49
#define ROWE 280         // bf16 elems/padded row: [Eph0 70][Eph1 70][Oph0 70][Oph1 70]

typedef unsigned int u32;

__device__ __forceinline__ int clampi(int v, int lo, int hi) {
    return v < lo ? lo : (v > hi ? hi : v);
}

__device__ __forceinline__ uint4 ld16(const __hip_bfloat16* src) {
    uint4 d; __builtin_memcpy(&d, src, 16); return d;   // 4B-aligned dwordx4
}

// 8 packed bf16 (4 dwords) -> 8 fp32. elem 2k = lo half of dword k.
__device__ __forceinline__ void unpack8(uint4 d, float* f) {
    f[0] = __uint_as_float(d.x << 16); f[1] = __uint_as_float(d.x & 0xffff0000u);
    f[2] = __uint_as_float(d.y << 16); f[3] = __uint_as_float(d.y & 0xffff0000u);
    f[4] = __uint_as_float(d.z << 16); f[5] = __uint_as_float(d.z & 0xffff0000u);
    f[6] = __uint_as_float(d.w << 16); f[7] = __uint_as_float(d.w & 0xffff0000u);
}

__device__ __forceinline__ unsigned short f2bf(float v) {
    __hip_bfloat16 b = __float2bfloat16(v);
    return *reinterpret_cast<unsigned short*>(&b);
}

// per-lane window offset: 7-neighbor window = first 7 elems of one aligned 16B load
__device__ __forceinline__ int lane_off(int w) {
    const int parity = w & 1, t = w >> 1, phase = t & 1;
    return parity * 140 + phase * 70 + (t - phase);
}

// ---------------------------------------------------------------------------
// K1: K/Q/V = relu(W @ x). Grid 1024 = xcd(8) x [pb16 x og8].
// K/V staged in LDS (8 KB), then written as cooperative dwordx4 chunks.
// Pad semantics: slot (plane parity P, phase f, local l) holds pixel
// clamp(2*(l - (f?2:3)) + P, 0, 127) -- PIXEL-space clamp (cross-parity at
// the edges), matching the original scalar store_kv byte-for-byte.
// ---------------------------------------------------------------------------
__global__ __launch_bounds__(256) void kqv_kernel(
    const float* __restrict__ x,  const float* __restrict__ Wk,
    const float* __restrict__ Wq, const float* __restrict__ Wv,
    __hip_bfloat16* __restrict__ Kp, __hip_bfloat16* __restrict__ Qt,
    __hip_bfloat16* __restrict__ Vp)
{
    __shared__ __hip_bfloat16 kv_lds[2][8][2][128];   // [arr][ch][row][w] = 8 KB

    const int xcd = blockIdx.x & 7;
    const int s   = blockIdx.x >> 3;          // 0..127
    const int pb  = xcd * 16 + (s & 15);      // 0..127
    const int og  = s >> 4;                   // 0..7
    const int p   = pb * 256 + threadIdx.x;   // 0..32767
    const int b   = p >> 14;
    const int hw  = p & 16383;
    const int w   = hw & 127;
    const int o0  = og * 8;
    const int row = threadIdx.x >> 7;         // 0/1 within block
    const float* xp = x + (size_t)b * CC * HWSZ + hw;

    float aK[8], aQ[8], aV[8];
#pragma unroll
    for (int i = 0; i < 8; ++i) { aK[i] = 0.f; aQ[i] = 0.f; aV[i] = 0.f; }

#pragma unroll 8
    for (int c = 0; c < CC; ++c) {
        const float xv = xp[(size_t)c * HWSZ];
#pragma unroll
        for (int i = 0; i < 8; ++i) {
            aK[i] = fmaf(Wk[(o0 + i) * CC + c], xv, aK[i]);
            aQ[i] = fmaf(Wq[(o0 + i) * CC + c], xv, aQ[i]);
            aV[i] = fmaf(Wv[(o0 + i) * CC + c], xv, aV[i]);
        }
    }

#pragma unroll
    for (int i = 0; i < 8; ++i) {
        kv_lds[0][i][row][w] = __float2bfloat16(fmaxf(aK[i], 0.f));
        kv_lds[1][i][row][w] = __float2bfloat16(fmaxf(aV[i], 0.f));
    }

    u32 qd[4];
#pragma unroll
    for (int i = 0; i < 4; ++i)
        qd[i] = (u32)f2bf(fmaxf(aQ[2 * i], 0.f)) |
                ((u32)f2bf(fmaxf(aQ[2 * i + 1], 0.f)) << 16);
    __builtin_memcpy(Qt + (size_t)p * CC + o0, qd, 16);   // 16B aligned

    __syncthreads();

    // ---- cooperative padded-row store: 32 rows x 35 chunks of 16B ----
    const int b0 = pb >> 6;            // block-uniform batch
    const int h0 = 2 * (pb & 63);      // block-uniform first row
    for (int idx = threadIdx.x; idx < 1120; idx += 256) {
        const int row_id = idx / 35;           // 0..31
        const int cki    = idx - row_id * 35;  // 0..34
        const int arr    = row_id >> 4;        // 0:K 1:V
        const int ch     = (row_id >> 1) & 7;
        const int rr     = row_id & 1;
        unsigned short e[8];
#pragma unroll
        for (int u = 0; u < 8; ++u) {
            const int q      = cki * 8 + u;           // 0..279
            const int parity = q >= 140 ? 1 : 0;
            const int sslot  = q - parity * 140;
            const int phase  = sslot >= 70 ? 1 : 0;
            const int local  = sslot - phase * 70;
            // PIXEL-space clamp (edge pads may cross parity):
            const int pix    = clampi(2 * (local - (phase ? 2 : 3)) + parity,
                                      0, 127);
            __hip_bfloat16 bv = kv_lds[arr][ch][rr][pix];
            e[u] = *reinterpret_cast<unsigned short*>(&bv);
        }
        __hip_bfloat16* dst = (arr ? Vp : Kp)
            + ((size_t)(b0 * CC + o0 + ch) * HH + (h0 + rr)) * ROWE + cki * 8;
        __builtin_memcpy(dst, e, 16);   // 16B-aligned dwordx4
    }
}

// ---------------------------------------------------------------------------
// K2: FUSED scores + softmax + V-aggregate, low-VGPR layout.
// Grid 1024 = xcd(8) x [bh32 x wseg4], 256 thr: px = tid&31, grp = tid>>5.
// Phase A: grp<7 computes score ROW i=grp over all 64 channels -> LDS.
// Softmax: per-thread from LDS (redundant x8, deterministic).
// Phase B: grp = 8-channel group; aggregates via 7 window loads/channel.
// ---------------------------------------------------------------------------
__global__ __launch_bounds__(256) void attn_kernel(
    const __hip_bfloat16* __restrict__ Kp, const __hip_bfloat16* __restrict__ Qt,
    const __hip_bfloat16* __restrict__ Vp, __hip_bfloat16* __restrict__ Ot)
{
    __shared__ __align__(16) float P_lds[32][52];

    const int xcd  = blockIdx.x & 7;
    const int s    = blockIdx.x >> 3;       // 0..127
    const int bh   = xcd * 32 + (s >> 2);   // 0..255
    const int wseg = s & 3;
    const int b    = bh >> 7;
    const int h    = bh & 127;

    const int tid = threadIdx.x;
    const int px  = tid & 31;
    const int grp = tid >> 5;               // 0..7
    const int w   = wseg * 32 + px;
    const int p   = b * HWSZ + h * WW + w;

    const int loff = lane_off(w);
    const size_t cstride = (size_t)HH * ROWE;

    // ---- Phase A: score row i = grp (7 of 8 groups active) ----
    if (grp < 7) {
        const int rowoff = clampi(h + 2 * grp - 6, 0, HH - 1) * ROWE;
        const __hip_bfloat16* Kc = Kp + (size_t)(b * CC) * cstride + rowoff + loff;
        const __hip_bfloat16* Qp = Qt + (size_t)p * CC;

        float sc7[KK];
#pragma unroll
        for (int j = 0; j < KK; ++j) sc7[j] = 0.f;

#pragma unroll 2
        for (int c8 = 0; c8 < 8; ++c8) {
            float qf[8];
            unpack8(ld16(Qp + c8 * 8), qf);
#pragma unroll
            for (int cc = 0; cc < 8; ++cc) {
                float kf[8];
                unpack8(ld16(Kc + (size_t)(c8 * 8 + cc) * cstride), kf);
#pragma unroll
                for (int j = 0; j < KK; ++j)
                    sc7[j] = fmaf(kf[j], qf[cc], sc7[j]);
            }
        }
#pragma unroll
        for (int j = 0; j < KK; ++j) P_lds[px][grp * KK + j] = sc7[j];
    }
    __syncthreads();

    // ---- softmax (per thread, redundant x8, deterministic) ----
    float pr[52];
#pragma unroll
    for (int t = 0; t < 13; ++t)
        ((float4*)pr)[t] = ((const float4*)&P_lds[px][0])[t];
    float m = pr[0];
#pragma unroll
    for (int k = 1; k < K2; ++k) m = fmaxf(m, pr[k]);
    float sum = 0.f;
#pragma unroll
    for (int k = 0; k < K2; ++k) { pr[k] = __expf(pr[k] - m); sum += pr[k]; }
    const float inv = 1.f / sum;
#pragma unroll
    for (int k = 0; k < K2; ++k) pr[k] *= inv;

    // ---- Phase B: V-aggregate for this group's 8 output channels ----
    int ro[KK];
#pragma unroll
    for (int i = 0; i < KK; ++i)
        ro[i] = clampi(h + 2 * i - 6, 0, HH - 1) * ROWE;

    const int c0 = grp * 8;
    const __hip_bfloat16* Vc = Vp + (size_t)(b * CC + c0) * cstride + loff;

    unsigned short ob[8];
#pragma unroll 2
    for (int ci = 0; ci < 8; ++ci) {
        const __hip_bfloat16* base = Vc + (size_t)ci * cstride;
        float acc = 0.f;
#pragma unroll
        for (int i = 0; i < KK; ++i) {
            float vf[8];
            unpack8(ld16(base + ro[i]), vf);
#pragma unroll
            for (int j = 0; j < KK; ++j)
                acc = fmaf(vf[j], pr[i * KK + j], acc);
        }
        ob[ci] = f2bf(acc);
    }

    u32 od[4];
#pragma unroll
    for (int i = 0; i < 4; ++i)
        od[i] = (u32)ob[2 * i] | ((u32)ob[2 * i + 1] << 16);
    __builtin_memcpy(Ot + (size_t)p * CC + c0, od, 16);   // 16B aligned
}

// ---------------------------------------------------------------------------
// K3: out = Wt @ O + x. Grid 1024 = xcd(8) x [pb16 x og8].
// ---------------------------------------------------------------------------
__global__ __launch_bounds__(256) void wt_kernel(
    const __hip_bfloat16* __restrict__ Ot, const float* __restrict__ x,
    const float* __restrict__ Wt, float* __restrict__ out)
{
    const int xcd = blockIdx.x & 7;
    const int s   = blockIdx.x >> 3;        // 0..127
    const int pb  = xcd * 16 + (s & 15);
    const int og  = s >> 4;
    const int p   = pb * 256 + threadIdx.x;
    const int b   = p >> 14;
    const int hw  = p & 16383;
    const int o0  = og * 8;

    float fin[8];
#pragma unroll
    for (int i = 0; i < 8; ++i)
        fin[i] = x[((size_t)b * CC + o0 + i) * HWSZ + hw];

    const __hip_bfloat16* op = Ot + (size_t)p * CC;
#pragma unroll
    for (int k = 0; k < 8; ++k) {
        float oc[8];
        unpack8(ld16(op + 8 * k), oc);
#pragma unroll
        for (int cc = 0; cc < 8; ++cc) {
            const int c = 8 * k + cc;
#pragma unroll
            for (int i = 0; i < 8; ++i)
                fin[i] = fmaf(Wt[(o0 + i) * CC + c], oc[cc], fin[i]);
        }
    }

#pragma unroll
    for (int i = 0; i < 8; ++i)
        out[((size_t)b * CC + o0 + i) * HWSZ + hw] = fin[i];
}

// ---------------------------------------------------------------------------
extern "C" void kernel_launch(void* const* d_in, const int* in_sizes, int n_in,
                              void* d_out, int out_size, void* d_ws, size_t ws_size,
                              hipStream_t stream)
{
    const float* x  = (const float*)d_in[0];
    const float* Wk = (const float*)d_in[1];
    const float* Wq = (const float*)d_in[2];
    const float* Wv = (const float*)d_in[3];
    const float* Wt = (const float*)d_in[4];
    float* out = (float*)d_out;

    const size_t KP_ELEMS = (size_t)BB * CC * HH * ROWE;  // 4,587,520 bf16
    const size_t QT_ELEMS = (size_t)BB * HWSZ * CC;       // 2,097,152 bf16
    __hip_bfloat16* Kp = (__hip_bfloat16*)d_ws;
    __hip_bfloat16* Vp = Kp + KP_ELEMS;
    __hip_bfloat16* Qt = Vp + KP_ELEMS;
    __hip_bfloat16* Ot = Qt + QT_ELEMS;                   // total ws 26.8 MB

    hipLaunchKernelGGL(kqv_kernel, dim3(1024), dim3(256), 0, stream,
                       x, Wk, Wq, Wv, Kp, Qt, Vp);
    hipLaunchKernelGGL(attn_kernel, dim3(1024), dim3(256), 0, stream,
                       Kp, Qt, Vp, Ot);
    hipLaunchKernelGGL(wt_kernel, dim3(1024), dim3(256), 0, stream,
                       Ot, x, Wt, out);
}

// Round 18
// 89.590 us; speedup vs baseline: 1.0798x; 1.0102x over previous
//
#include <hip/hip_runtime.h>
#include <hip/hip_bf16.h>

#define HH 128
#define WW 128
#define HWSZ (HH * WW)   // 16384
#define CC 64
#define BB 2
#define KK 7
#define K2 49
#define ROWE 280         // bf16 elems/padded row: [Eph0 70][Eph1 70][Oph0 70][Oph1 70]

typedef unsigned int u32;

__device__ __forceinline__ int clampi(int v, int lo, int hi) {
    return v < lo ? lo : (v > hi ? hi : v);
}

__device__ __forceinline__ uint4 ld16(const __hip_bfloat16* src) {
    uint4 d; __builtin_memcpy(&d, src, 16); return d;   // 4B-aligned dwordx4
}

// 8 packed bf16 (4 dwords) -> 8 fp32. elem 2k = lo half of dword k.
__device__ __forceinline__ void unpack8(uint4 d, float* f) {
    f[0] = __uint_as_float(d.x << 16); f[1] = __uint_as_float(d.x & 0xffff0000u);
    f[2] = __uint_as_float(d.y << 16); f[3] = __uint_as_float(d.y & 0xffff0000u);
    f[4] = __uint_as_float(d.z << 16); f[5] = __uint_as_float(d.z & 0xffff0000u);
    f[6] = __uint_as_float(d.w << 16); f[7] = __uint_as_float(d.w & 0xffff0000u);
}

__device__ __forceinline__ unsigned short f2bf(float v) {
    __hip_bfloat16 b = __float2bfloat16(v);
    return *reinterpret_cast<unsigned short*>(&b);
}

// per-lane window offset: 7-neighbor window = first 7 elems of one aligned 16B load
__device__ __forceinline__ int lane_off(int w) {
    const int parity = w & 1, t = w >> 1, phase = t & 1;
    return parity * 140 + phase * 70 + (t - phase);
}

// ---------------------------------------------------------------------------
// K1: K/Q/V = relu(W @ x). Grid 1024 = xcd(8) x [pb16 x og8].
// Channel loop batches 8 x-loads into xv[8] BEFORE the FMA block (explicit
// memory-level parallelism; r13-r16 showed VGPR=28 serialized the loads).
// K/V staged in LDS then stored as cooperative dwordx4 chunks (pixel-space
// clamped pads, byte-identical to the original scalar layout).
// ---------------------------------------------------------------------------
__global__ __launch_bounds__(256) void kqv_kernel(
    const float* __restrict__ x,  const float* __restrict__ Wk,
    const float* __restrict__ Wq, const float* __restrict__ Wv,
    __hip_bfloat16* __restrict__ Kp, __hip_bfloat16* __restrict__ Qt,
    __hip_bfloat16* __restrict__ Vp)
{
    __shared__ __hip_bfloat16 kv_lds[2][8][2][128];   // [arr][ch][row][w] = 8 KB

    const int xcd = blockIdx.x & 7;
    const int s   = blockIdx.x >> 3;          // 0..127
    const int pb  = xcd * 16 + (s & 15);      // 0..127
    const int og  = s >> 4;                   // 0..7
    const int p   = pb * 256 + threadIdx.x;   // 0..32767
    const int b   = p >> 14;
    const int hw  = p & 16383;
    const int w   = hw & 127;
    const int o0  = og * 8;
    const int row = threadIdx.x >> 7;         // 0/1 within block
    const float* xp = x + (size_t)b * CC * HWSZ + hw;

    float aK[8], aQ[8], aV[8];
#pragma unroll
    for (int i = 0; i < 8; ++i) { aK[i] = 0.f; aQ[i] = 0.f; aV[i] = 0.f; }

    for (int c8 = 0; c8 < 8; ++c8) {
        float xv[8];
#pragma unroll
        for (int u = 0; u < 8; ++u)
            xv[u] = xp[(size_t)(c8 * 8 + u) * HWSZ];
#pragma unroll
        for (int u = 0; u < 8; ++u) {
            const int c = c8 * 8 + u;
#pragma unroll
            for (int i = 0; i < 8; ++i) {
                aK[i] = fmaf(Wk[(o0 + i) * CC + c], xv[u], aK[i]);
                aQ[i] = fmaf(Wq[(o0 + i) * CC + c], xv[u], aQ[i]);
                aV[i] = fmaf(Wv[(o0 + i) * CC + c], xv[u], aV[i]);
            }
        }
    }

#pragma unroll
    for (int i = 0; i < 8; ++i) {
        kv_lds[0][i][row][w] = __float2bfloat16(fmaxf(aK[i], 0.f));
        kv_lds[1][i][row][w] = __float2bfloat16(fmaxf(aV[i], 0.f));
    }

    u32 qd[4];
#pragma unroll
    for (int i = 0; i < 4; ++i)
        qd[i] = (u32)f2bf(fmaxf(aQ[2 * i], 0.f)) |
                ((u32)f2bf(fmaxf(aQ[2 * i + 1], 0.f)) << 16);
    __builtin_memcpy(Qt + (size_t)p * CC + o0, qd, 16);   // 16B aligned

    __syncthreads();

    // ---- cooperative padded-row store: 32 rows x 35 chunks of 16B ----
    const int b0 = pb >> 6;            // block-uniform batch
    const int h0 = 2 * (pb & 63);      // block-uniform first row
    for (int idx = threadIdx.x; idx < 1120; idx += 256) {
        const int row_id = idx / 35;           // 0..31
        const int cki    = idx - row_id * 35;  // 0..34
        const int arr    = row_id >> 4;        // 0:K 1:V
        const int ch     = (row_id >> 1) & 7;
        const int rr     = row_id & 1;
        unsigned short e[8];
#pragma unroll
        for (int u = 0; u < 8; ++u) {
            const int q      = cki * 8 + u;           // 0..279
            const int parity = q >= 140 ? 1 : 0;
            const int sslot  = q - parity * 140;
            const int phase  = sslot >= 70 ? 1 : 0;
            const int local  = sslot - phase * 70;
            // PIXEL-space clamp (edge pads may cross parity):
            const int pix    = clampi(2 * (local - (phase ? 2 : 3)) + parity,
                                      0, 127);
            __hip_bfloat16 bv = kv_lds[arr][ch][rr][pix];
            e[u] = *reinterpret_cast<unsigned short*>(&bv);
        }
        __hip_bfloat16* dst = (arr ? Vp : Kp)
            + ((size_t)(b0 * CC + o0 + ch) * HH + (h0 + rr)) * ROWE + cki * 8;
        __builtin_memcpy(dst, e, 16);   // 16B-aligned dwordx4
    }
}

// ---------------------------------------------------------------------------
// K2: FUSED scores + softmax + V-aggregate, high-occupancy layout.
// Grid 2048 = xcd(8) x [bh32 x wseg8], 256 thr: px = tid&15 (pixel 0..15),
// grp = tid>>4 (0..15).
// Phase A: group g (row = g&7 < 7, half = g>>3) computes score row over its
//          32-channel half -> partials in P_par[2][16][52].
// Softmax: per-thread, pr = half0 + half1 (fixed order, deterministic).
// Phase B: group g aggregates 4 output channels (c0 = g*4).
// ---------------------------------------------------------------------------
__global__ __launch_bounds__(256) void attn_kernel(
    const __hip_bfloat16* __restrict__ Kp, const __hip_bfloat16* __restrict__ Qt,
    const __hip_bfloat16* __restrict__ Vp, __hip_bfloat16* __restrict__ Ot)
{
    __shared__ __align__(16) float P_par[2][16][52];

    const int xcd  = blockIdx.x & 7;
    const int s    = blockIdx.x >> 3;       // 0..255
    const int bh   = xcd * 32 + (s >> 3);   // 0..255
    const int wseg = s & 7;
    const int b    = bh >> 7;
    const int h    = bh & 127;

    const int tid = threadIdx.x;
    const int px  = tid & 15;
    const int grp = tid >> 4;               // 0..15
    const int w   = wseg * 16 + px;
    const int p   = b * HWSZ + h * WW + w;

    const int loff = lane_off(w);
    const size_t cstride = (size_t)HH * ROWE;

    // ---- Phase A: score row (grp&7), channel half (grp>>3) ----
    {
        const int srow = grp & 7;
        const int half = grp >> 3;
        if (srow < 7) {
            const int rowoff = clampi(h + 2 * srow - 6, 0, HH - 1) * ROWE;
            const __hip_bfloat16* Kc =
                Kp + (size_t)(b * CC + half * 32) * cstride + rowoff + loff;
            const __hip_bfloat16* Qp = Qt + (size_t)p * CC + half * 32;

            float sc7[KK];
#pragma unroll
            for (int j = 0; j < KK; ++j) sc7[j] = 0.f;

#pragma unroll
            for (int c8 = 0; c8 < 4; ++c8) {
                float qf[8];
                unpack8(ld16(Qp + c8 * 8), qf);
#pragma unroll
                for (int cc = 0; cc < 8; ++cc) {
                    float kf[8];
                    unpack8(ld16(Kc + (size_t)(c8 * 8 + cc) * cstride), kf);
#pragma unroll
                    for (int j = 0; j < KK; ++j)
                        sc7[j] = fmaf(kf[j], qf[cc], sc7[j]);
                }
            }
#pragma unroll
            for (int j = 0; j < KK; ++j)
                P_par[half][px][srow * KK + j] = sc7[j];
        }
    }
    __syncthreads();

    // ---- softmax (per thread, redundant x16, deterministic) ----
    float pr[52];
#pragma unroll
    for (int k = 0; k < K2; ++k)
        pr[k] = P_par[0][px][k] + P_par[1][px][k];
    float m = pr[0];
#pragma unroll
    for (int k = 1; k < K2; ++k) m = fmaxf(m, pr[k]);
    float sum = 0.f;
#pragma unroll
    for (int k = 0; k < K2; ++k) { pr[k] = __expf(pr[k] - m); sum += pr[k]; }
    const float inv = 1.f / sum;
#pragma unroll
    for (int k = 0; k < K2; ++k) pr[k] *= inv;

    // ---- Phase B: V-aggregate for this group's 4 output channels ----
    int ro[KK];
#pragma unroll
    for (int i = 0; i < KK; ++i)
        ro[i] = clampi(h + 2 * i - 6, 0, HH - 1) * ROWE;

    const int c0 = grp * 4;
    const __hip_bfloat16* Vc = Vp + (size_t)(b * CC + c0) * cstride + loff;

    unsigned short ob[4];
#pragma unroll
    for (int ci = 0; ci < 4; ++ci) {
        const __hip_bfloat16* base = Vc + (size_t)ci * cstride;
        float acc = 0.f;
#pragma unroll
        for (int i = 0; i < KK; ++i) {
            float vf[8];
            unpack8(ld16(base + ro[i]), vf);
#pragma unroll
            for (int j = 0; j < KK; ++j)
                acc = fmaf(vf[j], pr[i * KK + j], acc);
        }
        ob[ci] = f2bf(acc);
    }

    u32 od[2] = { (u32)ob[0] | ((u32)ob[1] << 16),
                  (u32)ob[2] | ((u32)ob[3] << 16) };
    __builtin_memcpy(Ot + (size_t)p * CC + c0, od, 8);   // 8B aligned
}

// ---------------------------------------------------------------------------
// K3: out = Wt @ O + x. Grid 1024 = xcd(8) x [pb16 x og8].
// ---------------------------------------------------------------------------
__global__ __launch_bounds__(256) void wt_kernel(
    const __hip_bfloat16* __restrict__ Ot, const float* __restrict__ x,
    const float* __restrict__ Wt, float* __restrict__ out)
{
    const int xcd = blockIdx.x & 7;
    const int s   = blockIdx.x >> 3;        // 0..127
    const int pb  = xcd * 16 + (s & 15);
    const int og  = s >> 4;
    const int p   = pb * 256 + threadIdx.x;
    const int b   = p >> 14;
    const int hw  = p & 16383;
    const int o0  = og * 8;

    float fin[8];
#pragma unroll
    for (int i = 0; i < 8; ++i)
        fin[i] = x[((size_t)b * CC + o0 + i) * HWSZ + hw];

    const __hip_bfloat16* op = Ot + (size_t)p * CC;
#pragma unroll
    for (int k = 0; k < 8; ++k) {
        float oc[8];
        unpack8(ld16(op + 8 * k), oc);
#pragma unroll
        for (int cc = 0; cc < 8; ++cc) {
            const int c = 8 * k + cc;
#pragma unroll
            for (int i = 0; i < 8; ++i)
                fin[i] = fmaf(Wt[(o0 + i) * CC + c], oc[cc], fin[i]);
        }
    }

#pragma unroll
    for (int i = 0; i < 8; ++i)
        out[((size_t)b * CC + o0 + i) * HWSZ + hw] = fin[i];
}

// ---------------------------------------------------------------------------
extern "C" void kernel_launch(void* const* d_in, const int* in_sizes, int n_in,
                              void* d_out, int out_size, void* d_ws, size_t ws_size,
                              hipStream_t stream)
{
    const float* x  = (const float*)d_in[0];
    const float* Wk = (const float*)d_in[1];
    const float* Wq = (const float*)d_in[2];
    const float* Wv = (const float*)d_in[3];
    const float* Wt = (const float*)d_in[4];
    float* out = (float*)d_out;

    const size_t KP_ELEMS = (size_t)BB * CC * HH * ROWE;  // 4,587,520 bf16
    const size_t QT_ELEMS = (size_t)BB * HWSZ * CC;       // 2,097,152 bf16
    __hip_bfloat16* Kp = (__hip_bfloat16*)d_ws;
    __hip_bfloat16* Vp = Kp + KP_ELEMS;
    __hip_bfloat16* Qt = Vp + KP_ELEMS;
    __hip_bfloat16* Ot = Qt + QT_ELEMS;                   // total ws 26.8 MB

    hipLaunchKernelGGL(kqv_kernel, dim3(1024), dim3(256), 0, stream,
                       x, Wk, Wq, Wv, Kp, Qt, Vp);
    hipLaunchKernelGGL(attn_kernel, dim3(2048), dim3(256), 0, stream,
                       Kp, Qt, Vp, Ot);
    hipLaunchKernelGGL(wt_kernel, dim3(1024), dim3(256), 0, stream,
                       Ot, x, Wt, out);
}

// Round 19
// 89.588 us; speedup vs baseline: 1.0798x; 1.0000x over previous
//
#include <hip/hip_runtime.h>
#include <hip/hip_bf16.h>

#define HH 128
#define WW 128
#define HWSZ (HH * WW)   // 16384
#define CC 64
#define BB 2
#define KK 7
#define K2 49
#define ROWE 280         // bf16 elems/padded row: [Eph0 70][Eph1 70][Oph0 70][Oph1 70]

typedef unsigned int u32;

__device__ __forceinline__ int clampi(int v, int lo, int hi) {
    return v < lo ? lo : (v > hi ? hi : v);
}

__device__ __forceinline__ uint4 ld16(const __hip_bfloat16* src) {
    uint4 d; __builtin_memcpy(&d, src, 16); return d;   // 4B-aligned dwordx4
}

// 8 packed bf16 (4 dwords) -> 8 fp32. elem 2k = lo half of dword k.
__device__ __forceinline__ void unpack8(uint4 d, float* f) {
    f[0] = __uint_as_float(d.x << 16); f[1] = __uint_as_float(d.x & 0xffff0000u);
    f[2] = __uint_as_float(d.y << 16); f[3] = __uint_as_float(d.y & 0xffff0000u);
    f[4] = __uint_as_float(d.z << 16); f[5] = __uint_as_float(d.z & 0xffff0000u);
    f[6] = __uint_as_float(d.w << 16); f[7] = __uint_as_float(d.w & 0xffff0000u);
}

__device__ __forceinline__ unsigned short f2bf(float v) {
    __hip_bfloat16 b = __float2bfloat16(v);
    return *reinterpret_cast<unsigned short*>(&b);
}

// per-lane window offset: 7-neighbor window = first 7 elems of one aligned 16B load
__device__ __forceinline__ int lane_off(int w) {
    const int parity = w & 1, t = w >> 1, phase = t & 1;
    return parity * 140 + phase * 70 + (t - phase);
}

// ---------------------------------------------------------------------------
// K1: K/Q/V = relu(W @ x). Grid 1024 = xcd(8) x [pb16 x og8].
// __launch_bounds__(256, 2): r13 showed the default occupancy-chasing
// allocator capped VGPR at 28 -- too small for the 24 accumulators, forcing
// a 3-pass loop split that re-read x three times (the stubborn ~41 us).
// The relaxed cap lets one pass keep all accums + xv[8] in registers.
// ---------------------------------------------------------------------------
__global__ __launch_bounds__(256, 2) void kqv_kernel(
    const float* __restrict__ x,  const float* __restrict__ Wk,
    const float* __restrict__ Wq, const float* __restrict__ Wv,
    __hip_bfloat16* __restrict__ Kp, __hip_bfloat16* __restrict__ Qt,
    __hip_bfloat16* __restrict__ Vp)
{
    __shared__ __hip_bfloat16 kv_lds[2][8][2][128];   // [arr][ch][row][w] = 8 KB

    const int xcd = blockIdx.x & 7;
    const int s   = blockIdx.x >> 3;          // 0..127
    const int pb  = xcd * 16 + (s & 15);      // 0..127
    const int og  = s >> 4;                   // 0..7
    const int p   = pb * 256 + threadIdx.x;   // 0..32767
    const int b   = p >> 14;
    const int hw  = p & 16383;
    const int w   = hw & 127;
    const int o0  = og * 8;
    const int row = threadIdx.x >> 7;         // 0/1 within block
    const float* xp = x + (size_t)b * CC * HWSZ + hw;

    float aK[8], aQ[8], aV[8];
#pragma unroll
    for (int i = 0; i < 8; ++i) { aK[i] = 0.f; aQ[i] = 0.f; aV[i] = 0.f; }

    for (int c8 = 0; c8 < 8; ++c8) {
        float xv[8];
#pragma unroll
        for (int u = 0; u < 8; ++u)
            xv[u] = xp[(size_t)(c8 * 8 + u) * HWSZ];
#pragma unroll
        for (int u = 0; u < 8; ++u) {
            const int c = c8 * 8 + u;
#pragma unroll
            for (int i = 0; i < 8; ++i) {
                aK[i] = fmaf(Wk[(o0 + i) * CC + c], xv[u], aK[i]);
                aQ[i] = fmaf(Wq[(o0 + i) * CC + c], xv[u], aQ[i]);
                aV[i] = fmaf(Wv[(o0 + i) * CC + c], xv[u], aV[i]);
            }
        }
    }

#pragma unroll
    for (int i = 0; i < 8; ++i) {
        kv_lds[0][i][row][w] = __float2bfloat16(fmaxf(aK[i], 0.f));
        kv_lds[1][i][row][w] = __float2bfloat16(fmaxf(aV[i], 0.f));
    }

    u32 qd[4];
#pragma unroll
    for (int i = 0; i < 4; ++i)
        qd[i] = (u32)f2bf(fmaxf(aQ[2 * i], 0.f)) |
                ((u32)f2bf(fmaxf(aQ[2 * i + 1], 0.f)) << 16);
    __builtin_memcpy(Qt + (size_t)p * CC + o0, qd, 16);   // 16B aligned

    __syncthreads();

    // ---- cooperative padded-row store: 32 rows x 35 chunks of 16B ----
    const int b0 = pb >> 6;            // block-uniform batch
    const int h0 = 2 * (pb & 63);      // block-uniform first row
    for (int idx = threadIdx.x; idx < 1120; idx += 256) {
        const int row_id = idx / 35;           // 0..31
        const int cki    = idx - row_id * 35;  // 0..34
        const int arr    = row_id >> 4;        // 0:K 1:V
        const int ch     = (row_id >> 1) & 7;
        const int rr     = row_id & 1;
        unsigned short e[8];
#pragma unroll
        for (int u = 0; u < 8; ++u) {
            const int q      = cki * 8 + u;           // 0..279
            const int parity = q >= 140 ? 1 : 0;
            const int sslot  = q - parity * 140;
            const int phase  = sslot >= 70 ? 1 : 0;
            const int local  = sslot - phase * 70;
            // PIXEL-space clamp (edge pads may cross parity):
            const int pix    = clampi(2 * (local - (phase ? 2 : 3)) + parity,
                                      0, 127);
            __hip_bfloat16 bv = kv_lds[arr][ch][rr][pix];
            e[u] = *reinterpret_cast<unsigned short*>(&bv);
        }
        __hip_bfloat16* dst = (arr ? Vp : Kp)
            + ((size_t)(b0 * CC + o0 + ch) * HH + (h0 + rr)) * ROWE + cki * 8;
        __builtin_memcpy(dst, e, 16);   // 16B-aligned dwordx4
    }
}

// ---------------------------------------------------------------------------
// K2: FUSED scores + softmax + V-aggregate, high-occupancy layout.
// Grid 2048 = xcd(8) x [bh32 x wseg8], 256 thr: px = tid&15 (pixel 0..15),
// grp = tid>>4 (0..15).
// Phase A: group g (row = g&7 < 7, half = g>>3) computes score row over its
//          32-channel half -> partials in P_par[2][16][52].
// Softmax: per-thread, pr = half0 + half1 (fixed order, deterministic).
// Phase B: group g aggregates 4 output channels (c0 = g*4).
// ---------------------------------------------------------------------------
__global__ __launch_bounds__(256) void attn_kernel(
    const __hip_bfloat16* __restrict__ Kp, const __hip_bfloat16* __restrict__ Qt,
    const __hip_bfloat16* __restrict__ Vp, __hip_bfloat16* __restrict__ Ot)
{
    __shared__ __align__(16) float P_par[2][16][52];

    const int xcd  = blockIdx.x & 7;
    const int s    = blockIdx.x >> 3;       // 0..255
    const int bh   = xcd * 32 + (s >> 3);   // 0..255
    const int wseg = s & 7;
    const int b    = bh >> 7;
    const int h    = bh & 127;

    const int tid = threadIdx.x;
    const int px  = tid & 15;
    const int grp = tid >> 4;               // 0..15
    const int w   = wseg * 16 + px;
    const int p   = b * HWSZ + h * WW + w;

    const int loff = lane_off(w);
    const size_t cstride = (size_t)HH * ROWE;

    // ---- Phase A: score row (grp&7), channel half (grp>>3) ----
    {
        const int srow = grp & 7;
        const int half = grp >> 3;
        if (srow < 7) {
            const int rowoff = clampi(h + 2 * srow - 6, 0, HH - 1) * ROWE;
            const __hip_bfloat16* Kc =
                Kp + (size_t)(b * CC + half * 32) * cstride + rowoff + loff;
            const __hip_bfloat16* Qp = Qt + (size_t)p * CC + half * 32;

            float sc7[KK];
#pragma unroll
            for (int j = 0; j < KK; ++j) sc7[j] = 0.f;

#pragma unroll
            for (int c8 = 0; c8 < 4; ++c8) {
                float qf[8];
                unpack8(ld16(Qp + c8 * 8), qf);
#pragma unroll
                for (int cc = 0; cc < 8; ++cc) {
                    float kf[8];
                    unpack8(ld16(Kc + (size_t)(c8 * 8 + cc) * cstride), kf);
#pragma unroll
                    for (int j = 0; j < KK; ++j)
                        sc7[j] = fmaf(kf[j], qf[cc], sc7[j]);
                }
            }
#pragma unroll
            for (int j = 0; j < KK; ++j)
                P_par[half][px][srow * KK + j] = sc7[j];
        }
    }
    __syncthreads();

    // ---- softmax (per thread, redundant x16, deterministic) ----
    float pr[52];
#pragma unroll
    for (int k = 0; k < K2; ++k)
        pr[k] = P_par[0][px][k] + P_par[1][px][k];
    float m = pr[0];
#pragma unroll
    for (int k = 1; k < K2; ++k) m = fmaxf(m, pr[k]);
    float sum = 0.f;
#pragma unroll
    for (int k = 0; k < K2; ++k) { pr[k] = __expf(pr[k] - m); sum += pr[k]; }
    const float inv = 1.f / sum;
#pragma unroll
    for (int k = 0; k < K2; ++k) pr[k] *= inv;

    // ---- Phase B: V-aggregate for this group's 4 output channels ----
    int ro[KK];
#pragma unroll
    for (int i = 0; i < KK; ++i)
        ro[i] = clampi(h + 2 * i - 6, 0, HH - 1) * ROWE;

    const int c0 = grp * 4;
    const __hip_bfloat16* Vc = Vp + (size_t)(b * CC + c0) * cstride + loff;

    unsigned short ob[4];
#pragma unroll
    for (int ci = 0; ci < 4; ++ci) {
        const __hip_bfloat16* base = Vc + (size_t)ci * cstride;
        float acc = 0.f;
#pragma unroll
        for (int i = 0; i < KK; ++i) {
            float vf[8];
            unpack8(ld16(base + ro[i]), vf);
#pragma unroll
            for (int j = 0; j < KK; ++j)
                acc = fmaf(vf[j], pr[i * KK + j], acc);
        }
        ob[ci] = f2bf(acc);
    }

    u32 od[2] = { (u32)ob[0] | ((u32)ob[1] << 16),
                  (u32)ob[2] | ((u32)ob[3] << 16) };
    __builtin_memcpy(Ot + (size_t)p * CC + c0, od, 8);   // 8B aligned
}

// ---------------------------------------------------------------------------
// K3: out = Wt @ O + x. Grid 1024 = xcd(8) x [pb16 x og8].
// ---------------------------------------------------------------------------
__global__ __launch_bounds__(256) void wt_kernel(
    const __hip_bfloat16* __restrict__ Ot, const float* __restrict__ x,
    const float* __restrict__ Wt, float* __restrict__ out)
{
    const int xcd = blockIdx.x & 7;
    const int s   = blockIdx.x >> 3;        // 0..127
    const int pb  = xcd * 16 + (s & 15);
    const int og  = s >> 4;
    const int p   = pb * 256 + threadIdx.x;
    const int b   = p >> 14;
    const int hw  = p & 16383;
    const int o0  = og * 8;

    float fin[8];
#pragma unroll
    for (int i = 0; i < 8; ++i)
        fin[i] = x[((size_t)b * CC + o0 + i) * HWSZ + hw];

    const __hip_bfloat16* op = Ot + (size_t)p * CC;
#pragma unroll
    for (int k = 0; k < 8; ++k) {
        float oc[8];
        unpack8(ld16(op + 8 * k), oc);
#pragma unroll
        for (int cc = 0; cc < 8; ++cc) {
            const int c = 8 * k + cc;
#pragma unroll
            for (int i = 0; i < 8; ++i)
                fin[i] = fmaf(Wt[(o0 + i) * CC + c], oc[cc], fin[i]);
        }
    }

#pragma unroll
    for (int i = 0; i < 8; ++i)
        out[((size_t)b * CC + o0 + i) * HWSZ + hw] = fin[i];
}

// ---------------------------------------------------------------------------
extern "C" void kernel_launch(void* const* d_in, const int* in_sizes, int n_in,
                              void* d_out, int out_size, void* d_ws, size_t ws_size,
                              hipStream_t stream)
{
    const float* x  = (const float*)d_in[0];
    const float* Wk = (const float*)d_in[1];
    const float* Wq = (const float*)d_in[2];
    const float* Wv = (const float*)d_in[3];
    const float* Wt = (const float*)d_in[4];
    float* out = (float*)d_out;

    const size_t KP_ELEMS = (size_t)BB * CC * HH * ROWE;  // 4,587,520 bf16
    const size_t QT_ELEMS = (size_t)BB * HWSZ * CC;       // 2,097,152 bf16
    __hip_bfloat16* Kp = (__hip_bfloat16*)d_ws;
    __hip_bfloat16* Vp = Kp + KP_ELEMS;
    __hip_bfloat16* Qt = Vp + KP_ELEMS;
    __hip_bfloat16* Ot = Qt + QT_ELEMS;                   // total ws 26.8 MB

    hipLaunchKernelGGL(kqv_kernel, dim3(1024), dim3(256), 0, stream,
                       x, Wk, Wq, Wv, Kp, Qt, Vp);
    hipLaunchKernelGGL(attn_kernel, dim3(2048), dim3(256), 0, stream,
                       Kp, Qt, Vp, Ot);
    hipLaunchKernelGGL(wt_kernel, dim3(1024), dim3(256), 0, stream,
                       Ot, x, Wt, out);
}

// Round 20
// 73.521 us; speedup vs baseline: 1.3158x; 1.2185x over previous
//
#include <hip/hip_runtime.h>
#include <hip/hip_bf16.h>

#define HH 128
#define WW 128
#define HWSZ (HH * WW)   // 16384
#define CC 64
#define BB 2
#define KK 7
#define K2 49
#define ROWE 280         // bf16 elems/padded row: [Eph0 70][Eph1 70][Oph0 70][Oph1 70]

typedef unsigned int u32;

__device__ __forceinline__ int clampi(int v, int lo, int hi) {
    return v < lo ? lo : (v > hi ? hi : v);
}

__device__ __forceinline__ uint4 ld16(const __hip_bfloat16* src) {
    uint4 d; __builtin_memcpy(&d, src, 16); return d;   // 4B-aligned dwordx4
}

// 8 packed bf16 (4 dwords) -> 8 fp32. elem 2k = lo half of dword k.
__device__ __forceinline__ void unpack8(uint4 d, float* f) {
    f[0] = __uint_as_float(d.x << 16); f[1] = __uint_as_float(d.x & 0xffff0000u);
    f[2] = __uint_as_float(d.y << 16); f[3] = __uint_as_float(d.y & 0xffff0000u);
    f[4] = __uint_as_float(d.z << 16); f[5] = __uint_as_float(d.z & 0xffff0000u);
    f[6] = __uint_as_float(d.w << 16); f[7] = __uint_as_float(d.w & 0xffff0000u);
}

__device__ __forceinline__ unsigned short f2bf(float v) {
    __hip_bfloat16 b = __float2bfloat16(v);
    return *reinterpret_cast<unsigned short*>(&b);
}

// per-lane window offset: 7-neighbor window = first 7 elems of one aligned 16B load
__device__ __forceinline__ int lane_off(int w) {
    const int parity = w & 1, t = w >> 1, phase = t & 1;
    return parity * 140 + phase * 70 + (t - phase);
}

// ---------------------------------------------------------------------------
// K1: K/Q/V = relu(W @ x) as a register-blocked GEMM.
// Grid 768 = xcd(8) x [pbl16 x slice6]; slice: array a = s>>1 (K/Q/V),
// och-half = s&1 (32 och). Block: 256 px (2 rows) x 32 och.
// Threads: quad = tid&63 (4 px), oct = tid>>6 (8 och).
// Weights staged ONCE in LDS (8 KB) -- kills the 1536 uniform weight
// re-loads/thread that pinned kqv at ~41 us through r13-r19.
// x loads: float4, fully coalesced (1 KB/wave-op).
// Epilogue: LDS restage + r16-verified padded-row chunk store (K/V) or
// transposed Qt chunk store (Q). Summation order c=0..63 unchanged ->
// outputs bit-identical to r16/r19.
// ---------------------------------------------------------------------------
__global__ __launch_bounds__(256) void kqv_kernel(
    const float* __restrict__ x,  const float* __restrict__ Wk,
    const float* __restrict__ Wq, const float* __restrict__ Wv,
    __hip_bfloat16* __restrict__ Kp, __hip_bfloat16* __restrict__ Qt,
    __hip_bfloat16* __restrict__ Vp)
{
    __shared__ __align__(16) float Wl[64][32];            // 8 KB [c][och_local]
    __shared__ __hip_bfloat16 T[32][2][128];              // 16 KB [ol][row][w]

    const int xcd   = blockIdx.x & 7;
    const int t     = blockIdx.x >> 3;        // 0..95
    const int pbl   = t & 15;
    const int slice = t >> 4;                 // 0..5
    const int pb    = xcd * 16 + pbl;         // 0..127
    const int a     = slice >> 1;             // 0:K 1:Q 2:V
    const int ohb   = (slice & 1) * 32;       // och base within array
    const int b0    = pb >> 6;
    const int h0    = 2 * (pb & 63);
    const int hw0   = (pb & 63) * 256;

    const float* Wsel = (a == 0) ? Wk : (a == 1) ? Wq : Wv;

    // stage weights: Wl[c][ol] = Wsel[(ohb+ol)*CC + c]
    for (int idx = threadIdx.x; idx < 2048; idx += 256) {
        const int c  = idx >> 5;
        const int ol = idx & 31;
        Wl[c][ol] = Wsel[(ohb + ol) * CC + c];
    }
    __syncthreads();

    const int quad = threadIdx.x & 63;        // 4 consecutive px
    const int oct  = threadIdx.x >> 6;        // 8 consecutive och

    const float* xbase = x + (size_t)b0 * CC * HWSZ + hw0 + quad * 4;

    float acc[8][4];
#pragma unroll
    for (int i = 0; i < 8; ++i)
#pragma unroll
        for (int j = 0; j < 4; ++j) acc[i][j] = 0.f;

#pragma unroll 4
    for (int c = 0; c < CC; ++c) {
        const float4 x4 = *(const float4*)(xbase + (size_t)c * HWSZ);
        const float xj[4] = {x4.x, x4.y, x4.z, x4.w};
        float w8[8];
        *(float4*)(w8)     = *(const float4*)&Wl[c][oct * 8];
        *(float4*)(w8 + 4) = *(const float4*)&Wl[c][oct * 8 + 4];
#pragma unroll
        for (int i = 0; i < 8; ++i)
#pragma unroll
            for (int j = 0; j < 4; ++j)
                acc[i][j] = fmaf(w8[i], xj[j], acc[i][j]);
    }

    // relu + bf16 into LDS tile
#pragma unroll
    for (int i = 0; i < 8; ++i) {
        const int ol = oct * 8 + i;
#pragma unroll
        for (int j = 0; j < 4; ++j) {
            const int px = quad * 4 + j;
            T[ol][px >> 7][px & 127] = __float2bfloat16(fmaxf(acc[i][j], 0.f));
        }
    }
    __syncthreads();

    if (a == 1) {
        // Q: transposed store Qt[p][och]: 256 px x 4 chunks of 8 och (16B)
        for (int idx = threadIdx.x; idx < 1024; idx += 256) {
            const int px = idx >> 2;
            const int ck = idx & 3;
            unsigned short e[8];
#pragma unroll
            for (int u = 0; u < 8; ++u) {
                __hip_bfloat16 bv = T[ck * 8 + u][px >> 7][px & 127];
                e[u] = *reinterpret_cast<unsigned short*>(&bv);
            }
            __hip_bfloat16* dst = Qt +
                (size_t)(b0 * HWSZ + hw0 + px) * CC + ohb + ck * 8;
            __builtin_memcpy(dst, e, 16);
        }
    } else {
        // K/V: padded-row store, 64 rows x 35 chunks (r16-verified mapping)
        __hip_bfloat16* arrp = (a == 0) ? Kp : Vp;
        for (int idx = threadIdx.x; idx < 2240; idx += 256) {
            const int row_id = idx / 35;           // 0..63
            const int cki    = idx - row_id * 35;  // 0..34
            const int ol     = row_id >> 1;
            const int rr     = row_id & 1;
            unsigned short e[8];
#pragma unroll
            for (int u = 0; u < 8; ++u) {
                const int q      = cki * 8 + u;           // 0..279
                const int parity = q >= 140 ? 1 : 0;
                const int sslot  = q - parity * 140;
                const int phase  = sslot >= 70 ? 1 : 0;
                const int local  = sslot - phase * 70;
                const int pix    = clampi(2 * (local - (phase ? 2 : 3)) + parity,
                                          0, 127);
                __hip_bfloat16 bv = T[ol][rr][pix];
                e[u] = *reinterpret_cast<unsigned short*>(&bv);
            }
            __hip_bfloat16* dst = arrp +
                ((size_t)(b0 * CC + ohb + ol) * HH + (h0 + rr)) * ROWE + cki * 8;
            __builtin_memcpy(dst, e, 16);
        }
    }
}

// ---------------------------------------------------------------------------
// K2: FUSED scores + softmax + V-aggregate.
// Grid 2048 = xcd(8) x [bh32 x wseg8], 256 thr.
// Phase A (px = tid&15, grp = tid>>4): row (grp&7), channel-half (grp>>3)
//   -> partials in P_par[2][16][52].
// Softmax: computed ONCE per pixel cooperatively (spx = tid>>4, slot =
//   tid&15; shfl_xor reduce over the 16 in-wave slots) -> P_sm[16][52].
//   (r19 recomputed it x16 per pixel -- ~10 us of redundant exp/VALU.)
// Phase B: pr[52] loaded from P_sm via 13 broadcast b128; 4 och/thread.
// ---------------------------------------------------------------------------
__global__ __launch_bounds__(256) void attn_kernel(
    const __hip_bfloat16* __restrict__ Kp, const __hip_bfloat16* __restrict__ Qt,
    const __hip_bfloat16* __restrict__ Vp, __hip_bfloat16* __restrict__ Ot)
{
    __shared__ __align__(16) float P_par[2][16][52];
    __shared__ __align__(16) float P_sm[16][52];

    const int xcd  = blockIdx.x & 7;
    const int s    = blockIdx.x >> 3;       // 0..255
    const int bh   = xcd * 32 + (s >> 3);   // 0..255
    const int wseg = s & 7;
    const int b    = bh >> 7;
    const int h    = bh & 127;

    const int tid = threadIdx.x;
    const int px  = tid & 15;
    const int grp = tid >> 4;               // 0..15
    const int w   = wseg * 16 + px;
    const int p   = b * HWSZ + h * WW + w;

    const int loff = lane_off(w);
    const size_t cstride = (size_t)HH * ROWE;

    // ---- Phase A: score row (grp&7), channel half (grp>>3) ----
    {
        const int srow = grp & 7;
        const int half = grp >> 3;
        if (srow < 7) {
            const int rowoff = clampi(h + 2 * srow - 6, 0, HH - 1) * ROWE;
            const __hip_bfloat16* Kc =
                Kp + (size_t)(b * CC + half * 32) * cstride + rowoff + loff;
            const __hip_bfloat16* Qp = Qt + (size_t)p * CC + half * 32;

            float sc7[KK];
#pragma unroll
            for (int j = 0; j < KK; ++j) sc7[j] = 0.f;

#pragma unroll
            for (int c8 = 0; c8 < 4; ++c8) {
                float qf[8];
                unpack8(ld16(Qp + c8 * 8), qf);
#pragma unroll
                for (int cc = 0; cc < 8; ++cc) {
                    float kf[8];
                    unpack8(ld16(Kc + (size_t)(c8 * 8 + cc) * cstride), kf);
#pragma unroll
                    for (int j = 0; j < KK; ++j)
                        sc7[j] = fmaf(kf[j], qf[cc], sc7[j]);
                }
            }
#pragma unroll
            for (int j = 0; j < KK; ++j)
                P_par[half][px][srow * KK + j] = sc7[j];
        }
    }
    __syncthreads();

    // ---- cooperative softmax: ONE computation per pixel ----
    {
        const int spx  = tid >> 4;          // pixel this thread helps
        const int slot = tid & 15;          // 16 slots per pixel (in-wave)
        float v[4];
        float lmax = -INFINITY;
#pragma unroll
        for (int m = 0; m < 4; ++m) {
            const int k = slot + 16 * m;
            v[m] = (k < K2) ? (P_par[0][spx][k] + P_par[1][spx][k]) : -INFINITY;
            lmax = fmaxf(lmax, v[m]);
        }
        float gmax = lmax;
#pragma unroll
        for (int msk = 1; msk < 16; msk <<= 1)
            gmax = fmaxf(gmax, __shfl_xor(gmax, msk, 64));
        float e[4], lsum = 0.f;
#pragma unroll
        for (int m = 0; m < 4; ++m) {
            const int k = slot + 16 * m;
            e[m] = (k < K2) ? __expf(v[m] - gmax) : 0.f;
            lsum += e[m];
        }
        float gsum = lsum;
#pragma unroll
        for (int msk = 1; msk < 16; msk <<= 1)
            gsum += __shfl_xor(gsum, msk, 64);
        const float inv = 1.f / gsum;
#pragma unroll
        for (int m = 0; m < 4; ++m) {
            const int k = slot + 16 * m;
            if (k < K2) P_sm[spx][k] = e[m] * inv;
            else if (k < 52) P_sm[spx][k] = 0.f;
        }
    }
    __syncthreads();

    // ---- load normalized probabilities (13 broadcast b128) ----
    float pr[52];
#pragma unroll
    for (int u = 0; u < 13; ++u)
        ((float4*)pr)[u] = ((const float4*)&P_sm[px][0])[u];

    // ---- Phase B: V-aggregate for this group's 4 output channels ----
    int ro[KK];
#pragma unroll
    for (int i = 0; i < KK; ++i)
        ro[i] = clampi(h + 2 * i - 6, 0, HH - 1) * ROWE;

    const int c0 = grp * 4;
    const __hip_bfloat16* Vc = Vp + (size_t)(b * CC + c0) * cstride + loff;

    unsigned short ob[4];
#pragma unroll
    for (int ci = 0; ci < 4; ++ci) {
        const __hip_bfloat16* base = Vc + (size_t)ci * cstride;
        float acc = 0.f;
#pragma unroll
        for (int i = 0; i < KK; ++i) {
            float vf[8];
            unpack8(ld16(base + ro[i]), vf);
#pragma unroll
            for (int j = 0; j < KK; ++j)
                acc = fmaf(vf[j], pr[i * KK + j], acc);
        }
        ob[ci] = f2bf(acc);
    }

    u32 od[2] = { (u32)ob[0] | ((u32)ob[1] << 16),
                  (u32)ob[2] | ((u32)ob[3] << 16) };
    __builtin_memcpy(Ot + (size_t)p * CC + c0, od, 8);   // 8B aligned
}

// ---------------------------------------------------------------------------
// K3: out = Wt @ O + x. Grid 1024 = xcd(8) x [pb16 x og8].
// ---------------------------------------------------------------------------
__global__ __launch_bounds__(256) void wt_kernel(
    const __hip_bfloat16* __restrict__ Ot, const float* __restrict__ x,
    const float* __restrict__ Wt, float* __restrict__ out)
{
    const int xcd = blockIdx.x & 7;
    const int s   = blockIdx.x >> 3;        // 0..127
    const int pb  = xcd * 16 + (s & 15);
    const int og  = s >> 4;
    const int p   = pb * 256 + threadIdx.x;
    const int b   = p >> 14;
    const int hw  = p & 16383;
    const int o0  = og * 8;

    float fin[8];
#pragma unroll
    for (int i = 0; i < 8; ++i)
        fin[i] = x[((size_t)b * CC + o0 + i) * HWSZ + hw];

    const __hip_bfloat16* op = Ot + (size_t)p * CC;
#pragma unroll
    for (int k = 0; k < 8; ++k) {
        float oc[8];
        unpack8(ld16(op + 8 * k), oc);
#pragma unroll
        for (int cc = 0; cc < 8; ++cc) {
            const int c = 8 * k + cc;
#pragma unroll
            for (int i = 0; i < 8; ++i)
                fin[i] = fmaf(Wt[(o0 + i) * CC + c], oc[cc], fin[i]);
        }
    }

#pragma unroll
    for (int i = 0; i < 8; ++i)
        out[((size_t)b * CC + o0 + i) * HWSZ + hw] = fin[i];
}

// ---------------------------------------------------------------------------
extern "C" void kernel_launch(void* const* d_in, const int* in_sizes, int n_in,
                              void* d_out, int out_size, void* d_ws, size_t ws_size,
                              hipStream_t stream)
{
    const float* x  = (const float*)d_in[0];
    const float* Wk = (const float*)d_in[1];
    const float* Wq = (const float*)d_in[2];
    const float* Wv = (const float*)d_in[3];
    const float* Wt = (const float*)d_in[4];
    float* out = (float*)d_out;

    const size_t KP_ELEMS = (size_t)BB * CC * HH * ROWE;  // 4,587,520 bf16
    const size_t QT_ELEMS = (size_t)BB * HWSZ * CC;       // 2,097,152 bf16
    __hip_bfloat16* Kp = (__hip_bfloat16*)d_ws;
    __hip_bfloat16* Vp = Kp + KP_ELEMS;
    __hip_bfloat16* Qt = Vp + KP_ELEMS;
    __hip_bfloat16* Ot = Qt + QT_ELEMS;                   // total ws 26.8 MB

    hipLaunchKernelGGL(kqv_kernel, dim3(768), dim3(256), 0, stream,
                       x, Wk, Wq, Wv, Kp, Qt, Vp);
    hipLaunchKernelGGL(attn_kernel, dim3(2048), dim3(256), 0, stream,
                       Kp, Qt, Vp, Ot);
    hipLaunchKernelGGL(wt_kernel, dim3(1024), dim3(256), 0, stream,
                       Ot, x, Wt, out);
}

// Round 21
// 72.015 us; speedup vs baseline: 1.3433x; 1.0209x over previous
//
#include <hip/hip_runtime.h>
#include <hip/hip_bf16.h>

#define HH 128
#define WW 128
#define HWSZ (HH * WW)   // 16384
#define CC 64
#define BB 2
#define KK 7
#define K2 49
#define ROWE 280         // bf16 elems/padded row: [Eph0 70][Eph1 70][Oph0 70][Oph1 70]

typedef unsigned int u32;

__device__ __forceinline__ int clampi(int v, int lo, int hi) {
    return v < lo ? lo : (v > hi ? hi : v);
}

__device__ __forceinline__ uint4 ld16(const __hip_bfloat16* src) {
    uint4 d; __builtin_memcpy(&d, src, 16); return d;   // 4B-aligned dwordx4
}

// 8 packed bf16 (4 dwords) -> 8 fp32. elem 2k = lo half of dword k.
__device__ __forceinline__ void unpack8(uint4 d, float* f) {
    f[0] = __uint_as_float(d.x << 16); f[1] = __uint_as_float(d.x & 0xffff0000u);
    f[2] = __uint_as_float(d.y << 16); f[3] = __uint_as_float(d.y & 0xffff0000u);
    f[4] = __uint_as_float(d.z << 16); f[5] = __uint_as_float(d.z & 0xffff0000u);
    f[6] = __uint_as_float(d.w << 16); f[7] = __uint_as_float(d.w & 0xffff0000u);
}

__device__ __forceinline__ unsigned short f2bf(float v) {
    __hip_bfloat16 b = __float2bfloat16(v);
    return *reinterpret_cast<unsigned short*>(&b);
}

// per-lane window offset: 7-neighbor window = first 7 elems of one aligned 16B load
__device__ __forceinline__ int lane_off(int w) {
    const int parity = w & 1, t = w >> 1, phase = t & 1;
    return parity * 140 + phase * 70 + (t - phase);
}

// ---------------------------------------------------------------------------
// K1: K/Q/V = relu(W @ x) as a register-blocked GEMM (r20, measured ~23 us).
// Grid 768 = xcd(8) x [pbl16 x slice6]. Weights staged once in LDS.
// ---------------------------------------------------------------------------
__global__ __launch_bounds__(256) void kqv_kernel(
    const float* __restrict__ x,  const float* __restrict__ Wk,
    const float* __restrict__ Wq, const float* __restrict__ Wv,
    __hip_bfloat16* __restrict__ Kp, __hip_bfloat16* __restrict__ Qt,
    __hip_bfloat16* __restrict__ Vp)
{
    __shared__ __align__(16) float Wl[64][32];            // 8 KB [c][och_local]
    __shared__ __hip_bfloat16 T[32][2][128];              // 16 KB [ol][row][w]

    const int xcd   = blockIdx.x & 7;
    const int t     = blockIdx.x >> 3;        // 0..95
    const int pbl   = t & 15;
    const int slice = t >> 4;                 // 0..5
    const int pb    = xcd * 16 + pbl;         // 0..127
    const int a     = slice >> 1;             // 0:K 1:Q 2:V
    const int ohb   = (slice & 1) * 32;       // och base within array
    const int b0    = pb >> 6;
    const int h0    = 2 * (pb & 63);
    const int hw0   = (pb & 63) * 256;

    const float* Wsel = (a == 0) ? Wk : (a == 1) ? Wq : Wv;

    for (int idx = threadIdx.x; idx < 2048; idx += 256) {
        const int c  = idx >> 5;
        const int ol = idx & 31;
        Wl[c][ol] = Wsel[(ohb + ol) * CC + c];
    }
    __syncthreads();

    const int quad = threadIdx.x & 63;        // 4 consecutive px
    const int oct  = threadIdx.x >> 6;        // 8 consecutive och

    const float* xbase = x + (size_t)b0 * CC * HWSZ + hw0 + quad * 4;

    float acc[8][4];
#pragma unroll
    for (int i = 0; i < 8; ++i)
#pragma unroll
        for (int j = 0; j < 4; ++j) acc[i][j] = 0.f;

#pragma unroll 4
    for (int c = 0; c < CC; ++c) {
        const float4 x4 = *(const float4*)(xbase + (size_t)c * HWSZ);
        const float xj[4] = {x4.x, x4.y, x4.z, x4.w};
        float w8[8];
        *(float4*)(w8)     = *(const float4*)&Wl[c][oct * 8];
        *(float4*)(w8 + 4) = *(const float4*)&Wl[c][oct * 8 + 4];
#pragma unroll
        for (int i = 0; i < 8; ++i)
#pragma unroll
            for (int j = 0; j < 4; ++j)
                acc[i][j] = fmaf(w8[i], xj[j], acc[i][j]);
    }

#pragma unroll
    for (int i = 0; i < 8; ++i) {
        const int ol = oct * 8 + i;
#pragma unroll
        for (int j = 0; j < 4; ++j) {
            const int px = quad * 4 + j;
            T[ol][px >> 7][px & 127] = __float2bfloat16(fmaxf(acc[i][j], 0.f));
        }
    }
    __syncthreads();

    if (a == 1) {
        for (int idx = threadIdx.x; idx < 1024; idx += 256) {
            const int px = idx >> 2;
            const int ck = idx & 3;
            unsigned short e[8];
#pragma unroll
            for (int u = 0; u < 8; ++u) {
                __hip_bfloat16 bv = T[ck * 8 + u][px >> 7][px & 127];
                e[u] = *reinterpret_cast<unsigned short*>(&bv);
            }
            __hip_bfloat16* dst = Qt +
                (size_t)(b0 * HWSZ + hw0 + px) * CC + ohb + ck * 8;
            __builtin_memcpy(dst, e, 16);
        }
    } else {
        __hip_bfloat16* arrp = (a == 0) ? Kp : Vp;
        for (int idx = threadIdx.x; idx < 2240; idx += 256) {
            const int row_id = idx / 35;           // 0..63
            const int cki    = idx - row_id * 35;  // 0..34
            const int ol     = row_id >> 1;
            const int rr     = row_id & 1;
            unsigned short e[8];
#pragma unroll
            for (int u = 0; u < 8; ++u) {
                const int q      = cki * 8 + u;           // 0..279
                const int parity = q >= 140 ? 1 : 0;
                const int sslot  = q - parity * 140;
                const int phase  = sslot >= 70 ? 1 : 0;
                const int local  = sslot - phase * 70;
                const int pix    = clampi(2 * (local - (phase ? 2 : 3)) + parity,
                                          0, 127);
                __hip_bfloat16 bv = T[ol][rr][pix];
                e[u] = *reinterpret_cast<unsigned short*>(&bv);
            }
            __hip_bfloat16* dst = arrp +
                ((size_t)(b0 * CC + ohb + ol) * HH + (h0 + rr)) * ROWE + cki * 8;
            __builtin_memcpy(dst, e, 16);
        }
    }
}

// ---------------------------------------------------------------------------
// K2: FUSED scores + softmax + V-aggregate -- r10 structure (best measured,
// ~33 us). Grid 1024 = xcd(8) x [bh32 x wseg4], 256 thr:
// px = (tid&15)|((tid>>7)<<4) (0..31), cq = (tid>>4)&7 (8 channels).
// Phase A: partial sc[49] over cq's 8 channels (7 window ld16/ch, Q amortized
//   1 ld16 per 8 ch). Wave = 16px x 4cq -> contiguous lane address runs.
// Reduce: shfl_xor(16)+shfl_xor(32) sums 4 cqs/wave -> 2 LDS slices, 1 barrier.
// Softmax: per thread (redundant x8, deterministic).
// Phase B: aggregate cq's 8 out-channels, one 16B bf16 store.
// ---------------------------------------------------------------------------
__global__ __launch_bounds__(256) void attn_kernel(
    const __hip_bfloat16* __restrict__ Kp, const __hip_bfloat16* __restrict__ Qt,
    const __hip_bfloat16* __restrict__ Vp, __hip_bfloat16* __restrict__ Ot)
{
    __shared__ float part[2][K2][33];

    const int xcd  = blockIdx.x & 7;
    const int s    = blockIdx.x >> 3;       // 0..127
    const int bh   = xcd * 32 + (s >> 2);   // 0..255
    const int wseg = s & 3;
    const int b    = bh >> 7;
    const int h    = bh & 127;

    const int tid = threadIdx.x;
    const int px  = (tid & 15) | ((tid >> 7) << 4);   // 0..31
    const int cq  = (tid >> 4) & 7;                   // 0..7
    const int w   = wseg * 32 + px;                   // 0..127
    const int p   = b * HWSZ + h * WW + w;
    const int c0  = cq * 8;

    int hn[KK];
#pragma unroll
    for (int i = 0; i < KK; ++i) hn[i] = clampi(h + 2 * i - 6, 0, HH - 1);

    const int loff = lane_off(w);
    const size_t cstride = (size_t)HH * ROWE;
    const __hip_bfloat16* Kc = Kp + (size_t)(b * CC + c0) * cstride + loff;
    const __hip_bfloat16* Vc = Vp + (size_t)(b * CC + c0) * cstride + loff;

    // Q for this thread's 8 channels: one 16B load
    float qf[8];
    unpack8(ld16(Qt + (size_t)p * CC + c0), qf);

    // ---- Phase A: partial scores over 8 channels ----
    float sc[K2];
#pragma unroll
    for (int k = 0; k < K2; ++k) sc[k] = 0.f;

    for (int ci = 0; ci < 8; ++ci) {
        uint4 kd[KK];
        const __hip_bfloat16* base = Kc + (size_t)ci * cstride;
#pragma unroll
        for (int i = 0; i < KK; ++i) kd[i] = ld16(base + (size_t)hn[i] * ROWE);
        const float qv = qf[ci];
#pragma unroll
        for (int i = 0; i < KK; ++i) {
            float kf[8];
            unpack8(kd[i], kf);
#pragma unroll
            for (int j = 0; j < KK; ++j)
                sc[i * KK + j] = fmaf(kf[j], qv, sc[i * KK + j]);
        }
    }

    // ---- cq-reduction: 4 cqs per wave via shfl, then 2 slices via LDS ----
#pragma unroll
    for (int k = 0; k < K2; ++k) sc[k] += __shfl_xor(sc[k], 16, 64);
#pragma unroll
    for (int k = 0; k < K2; ++k) sc[k] += __shfl_xor(sc[k], 32, 64);

    const int sl = (tid >> 6) & 1;          // wave's cq-set (0: cq0-3, 1: cq4-7)
    if (((tid >> 4) & 3) == 0) {            // one writer lane set per wave
#pragma unroll
        for (int k = 0; k < K2; ++k) part[sl][k][px] = sc[k];
    }
    __syncthreads();

    // ---- softmax (per thread, redundant x8, deterministic) ----
#pragma unroll
    for (int k = 0; k < K2; ++k) sc[k] = part[0][k][px] + part[1][k][px];
    float m = sc[0];
#pragma unroll
    for (int k = 1; k < K2; ++k) m = fmaxf(m, sc[k]);
    float sum = 0.f;
#pragma unroll
    for (int k = 0; k < K2; ++k) { sc[k] = __expf(sc[k] - m); sum += sc[k]; }
    const float inv = 1.f / sum;
#pragma unroll
    for (int k = 0; k < K2; ++k) sc[k] *= inv;

    // ---- Phase B: V-aggregate for this thread's 8 output channels ----
    unsigned short ob[8];
    for (int ci = 0; ci < 8; ++ci) {
        uint4 vd[KK];
        const __hip_bfloat16* base = Vc + (size_t)ci * cstride;
#pragma unroll
        for (int i = 0; i < KK; ++i) vd[i] = ld16(base + (size_t)hn[i] * ROWE);
        float acc = 0.f;
#pragma unroll
        for (int i = 0; i < KK; ++i) {
            float vf[8];
            unpack8(vd[i], vf);
#pragma unroll
            for (int j = 0; j < KK; ++j)
                acc = fmaf(vf[j], sc[i * KK + j], acc);
        }
        ob[ci] = f2bf(acc);
    }

    u32 od[4];
#pragma unroll
    for (int i = 0; i < 4; ++i)
        od[i] = (u32)ob[2 * i] | ((u32)ob[2 * i + 1] << 16);
    __builtin_memcpy(Ot + (size_t)p * CC + c0, od, 16);   // 16B aligned
}

// ---------------------------------------------------------------------------
// K3: out = Wt @ O + x. Grid 1024 = xcd(8) x [pb16 x og8].
// ---------------------------------------------------------------------------
__global__ __launch_bounds__(256) void wt_kernel(
    const __hip_bfloat16* __restrict__ Ot, const float* __restrict__ x,
    const float* __restrict__ Wt, float* __restrict__ out)
{
    const int xcd = blockIdx.x & 7;
    const int s   = blockIdx.x >> 3;        // 0..127
    const int pb  = xcd * 16 + (s & 15);
    const int og  = s >> 4;
    const int p   = pb * 256 + threadIdx.x;
    const int b   = p >> 14;
    const int hw  = p & 16383;
    const int o0  = og * 8;

    float fin[8];
#pragma unroll
    for (int i = 0; i < 8; ++i)
        fin[i] = x[((size_t)b * CC + o0 + i) * HWSZ + hw];

    const __hip_bfloat16* op = Ot + (size_t)p * CC;
#pragma unroll
    for (int k = 0; k < 8; ++k) {
        float oc[8];
        unpack8(ld16(op + 8 * k), oc);
#pragma unroll
        for (int cc = 0; cc < 8; ++cc) {
            const int c = 8 * k + cc;
#pragma unroll
            for (int i = 0; i < 8; ++i)
                fin[i] = fmaf(Wt[(o0 + i) * CC + c], oc[cc], fin[i]);
        }
    }

#pragma unroll
    for (int i = 0; i < 8; ++i)
        out[((size_t)b * CC + o0 + i) * HWSZ + hw] = fin[i];
}

// ---------------------------------------------------------------------------
extern "C" void kernel_launch(void* const* d_in, const int* in_sizes, int n_in,
                              void* d_out, int out_size, void* d_ws, size_t ws_size,
                              hipStream_t stream)
{
    const float* x  = (const float*)d_in[0];
    const float* Wk = (const float*)d_in[1];
    const float* Wq = (const float*)d_in[2];
    const float* Wv = (const float*)d_in[3];
    const float* Wt = (const float*)d_in[4];
    float* out = (float*)d_out;

    const size_t KP_ELEMS = (size_t)BB * CC * HH * ROWE;  // 4,587,520 bf16
    const size_t QT_ELEMS = (size_t)BB * HWSZ * CC;       // 2,097,152 bf16
    __hip_bfloat16* Kp = (__hip_bfloat16*)d_ws;
    __hip_bfloat16* Vp = Kp + KP_ELEMS;
    __hip_bfloat16* Qt = Vp + KP_ELEMS;
    __hip_bfloat16* Ot = Qt + QT_ELEMS;                   // total ws 26.8 MB

    hipLaunchKernelGGL(kqv_kernel, dim3(768), dim3(256), 0, stream,
                       x, Wk, Wq, Wv, Kp, Qt, Vp);
    hipLaunchKernelGGL(attn_kernel, dim3(1024), dim3(256), 0, stream,
                       Kp, Qt, Vp, Ot);
    hipLaunchKernelGGL(wt_kernel, dim3(1024), dim3(256), 0, stream,
                       Ot, x, Wt, out);
}

// Round 22
// 64.852 us; speedup vs baseline: 1.4917x; 1.1104x over previous
//
#include <hip/hip_runtime.h>
#include <hip/hip_bf16.h>

#define HH 128
#define WW 128
#define HWSZ (HH * WW)   // 16384
#define CC 64
#define BB 2
#define KK 7
#define K2 49
#define ROWE 280         // bf16 elems/padded row: [Eph0 70][Eph1 70][Oph0 70][Oph1 70]

typedef unsigned int u32;

__device__ __forceinline__ int clampi(int v, int lo, int hi) {
    return v < lo ? lo : (v > hi ? hi : v);
}

__device__ __forceinline__ uint4 ld16(const __hip_bfloat16* src) {
    uint4 d; __builtin_memcpy(&d, src, 16); return d;   // 4B-aligned dwordx4
}

// 8 packed bf16 (4 dwords) -> 8 fp32. elem 2k = lo half of dword k.
__device__ __forceinline__ void unpack8(uint4 d, float* f) {
    f[0] = __uint_as_float(d.x << 16); f[1] = __uint_as_float(d.x & 0xffff0000u);
    f[2] = __uint_as_float(d.y << 16); f[3] = __uint_as_float(d.y & 0xffff0000u);
    f[4] = __uint_as_float(d.z << 16); f[5] = __uint_as_float(d.z & 0xffff0000u);
    f[6] = __uint_as_float(d.w << 16); f[7] = __uint_as_float(d.w & 0xffff0000u);
}

__device__ __forceinline__ unsigned short f2bf(float v) {
    __hip_bfloat16 b = __float2bfloat16(v);
    return *reinterpret_cast<unsigned short*>(&b);
}

// per-lane window offset: 7-neighbor window = first 7 elems of one aligned 16B load
__device__ __forceinline__ int lane_off(int w) {
    const int parity = w & 1, t = w >> 1, phase = t & 1;
    return parity * 140 + phase * 70 + (t - phase);
}

// ---------------------------------------------------------------------------
// K1: K/Q/V = relu(W @ x) as a register-blocked GEMM (r20, measured ~23 us).
// Grid 768 = xcd(8) x [pbl16 x slice6]. Weights staged once in LDS.
// ---------------------------------------------------------------------------
__global__ __launch_bounds__(256) void kqv_kernel(
    const float* __restrict__ x,  const float* __restrict__ Wk,
    const float* __restrict__ Wq, const float* __restrict__ Wv,
    __hip_bfloat16* __restrict__ Kp, __hip_bfloat16* __restrict__ Qt,
    __hip_bfloat16* __restrict__ Vp)
{
    __shared__ __align__(16) float Wl[64][32];            // 8 KB [c][och_local]
    __shared__ __hip_bfloat16 T[32][2][128];              // 16 KB [ol][row][w]

    const int xcd   = blockIdx.x & 7;
    const int t     = blockIdx.x >> 3;        // 0..95
    const int pbl   = t & 15;
    const int slice = t >> 4;                 // 0..5
    const int pb    = xcd * 16 + pbl;         // 0..127
    const int a     = slice >> 1;             // 0:K 1:Q 2:V
    const int ohb   = (slice & 1) * 32;       // och base within array
    const int b0    = pb >> 6;
    const int h0    = 2 * (pb & 63);
    const int hw0   = (pb & 63) * 256;

    const float* Wsel = (a == 0) ? Wk : (a == 1) ? Wq : Wv;

    for (int idx = threadIdx.x; idx < 2048; idx += 256) {
        const int c  = idx >> 5;
        const int ol = idx & 31;
        Wl[c][ol] = Wsel[(ohb + ol) * CC + c];
    }
    __syncthreads();

    const int quad = threadIdx.x & 63;        // 4 consecutive px
    const int oct  = threadIdx.x >> 6;        // 8 consecutive och

    const float* xbase = x + (size_t)b0 * CC * HWSZ + hw0 + quad * 4;

    float acc[8][4];
#pragma unroll
    for (int i = 0; i < 8; ++i)
#pragma unroll
        for (int j = 0; j < 4; ++j) acc[i][j] = 0.f;

#pragma unroll 4
    for (int c = 0; c < CC; ++c) {
        const float4 x4 = *(const float4*)(xbase + (size_t)c * HWSZ);
        const float xj[4] = {x4.x, x4.y, x4.z, x4.w};
        float w8[8];
        *(float4*)(w8)     = *(const float4*)&Wl[c][oct * 8];
        *(float4*)(w8 + 4) = *(const float4*)&Wl[c][oct * 8 + 4];
#pragma unroll
        for (int i = 0; i < 8; ++i)
#pragma unroll
            for (int j = 0; j < 4; ++j)
                acc[i][j] = fmaf(w8[i], xj[j], acc[i][j]);
    }

#pragma unroll
    for (int i = 0; i < 8; ++i) {
        const int ol = oct * 8 + i;
#pragma unroll
        for (int j = 0; j < 4; ++j) {
            const int px = quad * 4 + j;
            T[ol][px >> 7][px & 127] = __float2bfloat16(fmaxf(acc[i][j], 0.f));
        }
    }
    __syncthreads();

    if (a == 1) {
        for (int idx = threadIdx.x; idx < 1024; idx += 256) {
            const int px = idx >> 2;
            const int ck = idx & 3;
            unsigned short e[8];
#pragma unroll
            for (int u = 0; u < 8; ++u) {
                __hip_bfloat16 bv = T[ck * 8 + u][px >> 7][px & 127];
                e[u] = *reinterpret_cast<unsigned short*>(&bv);
            }
            __hip_bfloat16* dst = Qt +
                (size_t)(b0 * HWSZ + hw0 + px) * CC + ohb + ck * 8;
            __builtin_memcpy(dst, e, 16);
        }
    } else {
        __hip_bfloat16* arrp = (a == 0) ? Kp : Vp;
        for (int idx = threadIdx.x; idx < 2240; idx += 256) {
            const int row_id = idx / 35;           // 0..63
            const int cki    = idx - row_id * 35;  // 0..34
            const int ol     = row_id >> 1;
            const int rr     = row_id & 1;
            unsigned short e[8];
#pragma unroll
            for (int u = 0; u < 8; ++u) {
                const int q      = cki * 8 + u;           // 0..279
                const int parity = q >= 140 ? 1 : 0;
                const int sslot  = q - parity * 140;
                const int phase  = sslot >= 70 ? 1 : 0;
                const int local  = sslot - phase * 70;
                const int pix    = clampi(2 * (local - (phase ? 2 : 3)) + parity,
                                          0, 127);
                __hip_bfloat16 bv = T[ol][rr][pix];
                e[u] = *reinterpret_cast<unsigned short*>(&bv);
            }
            __hip_bfloat16* dst = arrp +
                ((size_t)(b0 * CC + ohb + ol) * HH + (h0 + rr)) * ROWE + cki * 8;
            __builtin_memcpy(dst, e, 16);
        }
    }
}

// ---------------------------------------------------------------------------
// K2: FULLY FUSED attention: scores + softmax + V-aggregate + Wt conv +
// residual (wt kernel absorbed -- kills the Ot round-trip and one launch).
// Grid 1024 = xcd(8) x [bh32 x wseg4], 256 thr:
// px = (tid&15)|((tid>>7)<<4) (0..31), cq = (tid>>4)&7 (8 channels).
// Epilogue: O exchanged via LDS (padded [32][72] breaks px-stride bank
// conflict), Wt staged in LDS (16 KB, broadcast reads), c=0..63 order kept.
// ---------------------------------------------------------------------------
__global__ __launch_bounds__(256) void attn_kernel(
    const __hip_bfloat16* __restrict__ Kp, const __hip_bfloat16* __restrict__ Qt,
    const __hip_bfloat16* __restrict__ Vp, const float* __restrict__ Wt,
    const float* __restrict__ x, float* __restrict__ out)
{
    __shared__ float part[2][K2][33];
    __shared__ __align__(16) float Wt_l[64][64];           // 16 KB
    __shared__ __align__(16) __hip_bfloat16 O_l[32][72];   // 4.5 KB (padded)

    const int xcd  = blockIdx.x & 7;
    const int s    = blockIdx.x >> 3;       // 0..127
    const int bh   = xcd * 32 + (s >> 2);   // 0..255
    const int wseg = s & 3;
    const int b    = bh >> 7;
    const int h    = bh & 127;

    const int tid = threadIdx.x;
    const int px  = (tid & 15) | ((tid >> 7) << 4);   // 0..31
    const int cq  = (tid >> 4) & 7;                   // 0..7
    const int w   = wseg * 32 + px;                   // 0..127
    const int p   = b * HWSZ + h * WW + w;
    const int c0  = cq * 8;

    // stage Wt (overlaps phase A; covered by the post-phase-A barrier)
    for (int idx = tid; idx < 4096; idx += 256)
        Wt_l[idx >> 6][idx & 63] = Wt[idx];

    int hn[KK];
#pragma unroll
    for (int i = 0; i < KK; ++i) hn[i] = clampi(h + 2 * i - 6, 0, HH - 1);

    const int loff = lane_off(w);
    const size_t cstride = (size_t)HH * ROWE;
    const __hip_bfloat16* Kc = Kp + (size_t)(b * CC + c0) * cstride + loff;
    const __hip_bfloat16* Vc = Vp + (size_t)(b * CC + c0) * cstride + loff;

    float qf[8];
    unpack8(ld16(Qt + (size_t)p * CC + c0), qf);

    // ---- Phase A: partial scores over 8 channels ----
    float sc[K2];
#pragma unroll
    for (int k = 0; k < K2; ++k) sc[k] = 0.f;

    for (int ci = 0; ci < 8; ++ci) {
        uint4 kd[KK];
        const __hip_bfloat16* base = Kc + (size_t)ci * cstride;
#pragma unroll
        for (int i = 0; i < KK; ++i) kd[i] = ld16(base + (size_t)hn[i] * ROWE);
        const float qv = qf[ci];
#pragma unroll
        for (int i = 0; i < KK; ++i) {
            float kf[8];
            unpack8(kd[i], kf);
#pragma unroll
            for (int j = 0; j < KK; ++j)
                sc[i * KK + j] = fmaf(kf[j], qv, sc[i * KK + j]);
        }
    }

    // ---- cq-reduction: 4 cqs per wave via shfl, then 2 slices via LDS ----
#pragma unroll
    for (int k = 0; k < K2; ++k) sc[k] += __shfl_xor(sc[k], 16, 64);
#pragma unroll
    for (int k = 0; k < K2; ++k) sc[k] += __shfl_xor(sc[k], 32, 64);

    const int sl = (tid >> 6) & 1;
    if (((tid >> 4) & 3) == 0) {
#pragma unroll
        for (int k = 0; k < K2; ++k) part[sl][k][px] = sc[k];
    }
    __syncthreads();

    // ---- softmax (per thread, redundant x8, deterministic) ----
#pragma unroll
    for (int k = 0; k < K2; ++k) sc[k] = part[0][k][px] + part[1][k][px];
    float m = sc[0];
#pragma unroll
    for (int k = 1; k < K2; ++k) m = fmaxf(m, sc[k]);
    float sum = 0.f;
#pragma unroll
    for (int k = 0; k < K2; ++k) { sc[k] = __expf(sc[k] - m); sum += sc[k]; }
    const float inv = 1.f / sum;
#pragma unroll
    for (int k = 0; k < K2; ++k) sc[k] *= inv;

    // residual loads early (independent of phase B; hides under PV compute)
    const int hw = h * WW + w;
    float fin[8];
#pragma unroll
    for (int i = 0; i < 8; ++i)
        fin[i] = x[((size_t)(b * CC) + c0 + i) * HWSZ + hw];

    // ---- Phase B: V-aggregate for this thread's 8 output channels ----
    unsigned short ob[8];
    for (int ci = 0; ci < 8; ++ci) {
        uint4 vd[KK];
        const __hip_bfloat16* base = Vc + (size_t)ci * cstride;
#pragma unroll
        for (int i = 0; i < KK; ++i) vd[i] = ld16(base + (size_t)hn[i] * ROWE);
        float acc = 0.f;
#pragma unroll
        for (int i = 0; i < KK; ++i) {
            float vf[8];
            unpack8(vd[i], vf);
#pragma unroll
            for (int j = 0; j < KK; ++j)
                acc = fmaf(vf[j], sc[i * KK + j], acc);
        }
        ob[ci] = f2bf(acc);
    }

    u32 od[4];
#pragma unroll
    for (int i = 0; i < 4; ++i)
        od[i] = (u32)ob[2 * i] | ((u32)ob[2 * i + 1] << 16);
    __builtin_memcpy(&O_l[px][c0], od, 16);
    __syncthreads();

    // ---- fused Wt conv + residual (wt kernel absorbed) ----
    // thread (px, og=cq) computes out channels o0=cq*8..+8 for its pixel.
#pragma unroll
    for (int c8 = 0; c8 < 8; ++c8) {
        uint4 d = *(const uint4*)&O_l[px][c8 * 8];
        float oc[8];
        unpack8(d, oc);
#pragma unroll
        for (int cc = 0; cc < 8; ++cc) {
            const int c = c8 * 8 + cc;
#pragma unroll
            for (int i = 0; i < 8; ++i)
                fin[i] = fmaf(Wt_l[c0 + i][c], oc[cc], fin[i]);
        }
    }

#pragma unroll
    for (int i = 0; i < 8; ++i)
        out[((size_t)(b * CC) + c0 + i) * HWSZ + hw] = fin[i];
}

// ---------------------------------------------------------------------------
extern "C" void kernel_launch(void* const* d_in, const int* in_sizes, int n_in,
                              void* d_out, int out_size, void* d_ws, size_t ws_size,
                              hipStream_t stream)
{
    const float* x  = (const float*)d_in[0];
    const float* Wk = (const float*)d_in[1];
    const float* Wq = (const float*)d_in[2];
    const float* Wv = (const float*)d_in[3];
    const float* Wt = (const float*)d_in[4];
    float* out = (float*)d_out;

    const size_t KP_ELEMS = (size_t)BB * CC * HH * ROWE;  // 4,587,520 bf16
    __hip_bfloat16* Kp = (__hip_bfloat16*)d_ws;
    __hip_bfloat16* Vp = Kp + KP_ELEMS;
    __hip_bfloat16* Qt = Vp + KP_ELEMS;                   // total ws 22.6 MB

    hipLaunchKernelGGL(kqv_kernel, dim3(768), dim3(256), 0, stream,
                       x, Wk, Wq, Wv, Kp, Qt, Vp);
    hipLaunchKernelGGL(attn_kernel, dim3(1024), dim3(256), 0, stream,
                       Kp, Qt, Vp, Wt, x, out);
}